// Round 5
// baseline (242.767 us; speedup 1.0000x reference)
//
#include <hip/hip_runtime.h>

#define G_DIM 16384
#define N_BATCH 2048
#define IN_DIM 1024
#define NLAYER 6
#define THREADS 1024
#define GPT 16                 // gates per thread
#define ROWS_PER_BLOCK 2

// LLVM SchedGroupMask bits (per learn_hip m137 / CK arch.hpp)
#define SGB_VALU      0x002
#define SGB_VMEM_READ 0x020
#define SGB_DS_READ   0x100

struct Ptrs {
    const int*   idx[NLAYER];
    const float* w[NLAYER];
};

__device__ __forceinline__ float4 softmax_coef(const float* __restrict__ w, int g) {
    float v[16];
    float m = -1e30f;
#pragma unroll
    for (int k = 0; k < 16; ++k) { v[k] = w[k * G_DIM + g]; m = fmaxf(m, v[k]); }
    float s = 0.f;
#pragma unroll
    for (int k = 0; k < 16; ++k) { v[k] = expf(v[k] - m); s += v[k]; }
    const float inv = 1.f / s;
    float4 c;
    c.x = (v[8]+v[9]+v[10]+v[11]+v[12]+v[13]+v[14]+v[15]) * inv;
    c.y = (v[2]+v[3]+v[6]+v[7] - v[8]-v[9]-v[12]-v[13]) * inv;
    c.z = (v[4]+v[5]+v[6]+v[7] - v[8]-v[9]-v[10]-v[11]) * inv;
    c.w = (v[1]-v[2]-v[4]-2.f*v[6]-v[7]+v[8]+2.f*v[9]+v[11]+v[13]-v[14]) * inv;
    return c;
}

// ---- precompute: coef[l][g] (float4) and packed idx (lo16 = A, hi16 = B) ----
__global__ __launch_bounds__(256) void pack_kernel(Ptrs P, float4* __restrict__ coef,
                                                   unsigned* __restrict__ sidx) {
    const int g = blockIdx.x * blockDim.x + threadIdx.x;
    const int l = blockIdx.y;
    coef[(size_t)l * G_DIM + g] = softmax_coef(P.w[l], g);
    const int2 p = ((const int2*)P.idx[l])[g];
    sidx[(size_t)l * G_DIM + g] = (unsigned)p.x | ((unsigned)p.y << 16);
}

// ---- main fused kernel: 2 rows/block interleaved float2 in LDS.
//      sched_group_barrier pins: all 16 coef VMEM_READ issue FIRST, then
//      per-gate {2 DS_READ + VALU} with counted vmcnt waits -> the L2 coef
//      stream overlaps the LDS gather phase instead of alternating with it. ----
__global__ __launch_bounds__(THREADS, 4) void fused_ws_kernel(
    const float* __restrict__ x,
    const float4* __restrict__ coef,
    const unsigned* __restrict__ sidx,
    const float* __restrict__ lin_w,
    const float* __restrict__ lin_b,
    float* __restrict__ out)
{
    __shared__ float2 buf[G_DIM];            // 128 KB: .x = row0, .y = row1
    __shared__ float red0[THREADS / 64];
    __shared__ float red1[THREADS / 64];

    const int tid  = threadIdx.x;
    const int row0 = blockIdx.x * ROWS_PER_BLOCK;

    for (int i = tid; i < IN_DIM; i += THREADS) {
        buf[i] = make_float2(x[(size_t)row0 * IN_DIM + i],
                             x[(size_t)(row0 + 1) * IN_DIM + i]);
    }

    // hoist layer-0 packed indices while rows load
    unsigned pa[GPT];
#pragma unroll
    for (int i = 0; i < GPT; ++i) pa[i] = sidx[tid + i * THREADS];

    __syncthreads();

    float a0 = 0.f, a1 = 0.f;   // final dot accumulators (last layer feeds these)

#pragma unroll
    for (int l = 0; l < NLAYER; ++l) {
        const float4* __restrict__ cl = coef + (size_t)l * G_DIM;

        // issue ALL coef loads for this layer (16 float4 in flight)
        float4 c[GPT];
#pragma unroll
        for (int i = 0; i < GPT; ++i) c[i] = cl[tid + i * THREADS];

        // gather + fma; counted vmcnt per c[i] use overlaps LDS with L2 stream
        float2 o[GPT];
#pragma unroll
        for (int i = 0; i < GPT; ++i) {
            const unsigned pk = pa[i];
            const float2 Ap = buf[pk & 0xFFFFu];
            const float2 Bp = buf[pk >> 16];
            o[i].x = fmaf(fmaf(c[i].w, Bp.x, c[i].y), Ap.x, fmaf(c[i].z, Bp.x, c[i].x));
            o[i].y = fmaf(fmaf(c[i].w, Bp.y, c[i].y), Ap.y, fmaf(c[i].z, Bp.y, c[i].x));
        }

        // prefetch next layer's packed indices (issue after coef cluster)
        unsigned pn[GPT];
        if (l + 1 < NLAYER) {
            const unsigned* __restrict__ sl = sidx + (size_t)(l + 1) * G_DIM;
#pragma unroll
            for (int i = 0; i < GPT; ++i) pn[i] = sl[tid + i * THREADS];
        }

        // --- schedule pinning for this region (between barriers) ---
        __builtin_amdgcn_sched_group_barrier(SGB_VMEM_READ, GPT, 0);  // 16 coef loads first
#pragma unroll
        for (int i = 0; i < GPT; ++i) {
            __builtin_amdgcn_sched_group_barrier(SGB_DS_READ, 2, 0);  // gate's 2 gathers
            __builtin_amdgcn_sched_group_barrier(SGB_VALU, 10, 0);    // its addr+fma work
        }
        __builtin_amdgcn_sched_group_barrier(SGB_VMEM_READ, GPT, 0);  // next-layer idx

        if (l + 1 < NLAYER) {
            __syncthreads();   // all reads of this layer done
#pragma unroll
            for (int i = 0; i < GPT; ++i) buf[tid + i * THREADS] = o[i];
            __syncthreads();   // layer fully materialized
#pragma unroll
            for (int i = 0; i < GPT; ++i) pa[i] = pn[i];
        } else {
            // last layer: o[] holds this thread's 16 gates -> dot directly,
            // no LDS write-back / re-read needed
#pragma unroll
            for (int i = 0; i < GPT; ++i) {
                const float lw = lin_w[tid + i * THREADS];
                a0 = fmaf(o[i].x, lw, a0);
                a1 = fmaf(o[i].y, lw, a1);
            }
        }
    }

    // cross-lane / cross-wave reduction
#pragma unroll
    for (int off = 32; off > 0; off >>= 1) {
        a0 += __shfl_down(a0, off);
        a1 += __shfl_down(a1, off);
    }
    const int lane = tid & 63, wid = tid >> 6;
    if (lane == 0) { red0[wid] = a0; red1[wid] = a1; }
    __syncthreads();
    if (tid == 0) {
        float s0 = 0.f, s1 = 0.f;
#pragma unroll
        for (int k = 0; k < THREADS / 64; ++k) { s0 += red0[k]; s1 += red1[k]; }
        const float lb = lin_b[0];
        out[row0]     = s0 + lb;
        out[row0 + 1] = s1 + lb;
    }
}

// ---- fallback (small ws): inline softmax, direct int2 idx (correctness only) ----
__global__ __launch_bounds__(THREADS, 1) void fused_fallback_kernel(
    const float* __restrict__ x, Ptrs P,
    const float* __restrict__ lin_w, const float* __restrict__ lin_b,
    float* __restrict__ out)
{
    __shared__ float2 buf[G_DIM];
    __shared__ float red0[THREADS / 64];
    __shared__ float red1[THREADS / 64];
    const int tid  = threadIdx.x;
    const int row0 = blockIdx.x * ROWS_PER_BLOCK;
    for (int i = tid; i < IN_DIM; i += THREADS)
        buf[i] = make_float2(x[(size_t)row0 * IN_DIM + i],
                             x[(size_t)(row0 + 1) * IN_DIM + i]);
    __syncthreads();
    float2 o[GPT];
    for (int l = 0; l < NLAYER; ++l) {
        const int2* __restrict__ idxl = (const int2*)P.idx[l];
#pragma unroll
        for (int i = 0; i < GPT; ++i) {
            const int g = tid + i * THREADS;
            const int2 p = idxl[g];
            const float4 c = softmax_coef(P.w[l], g);
            const float2 Ap = buf[p.x];
            const float2 Bp = buf[p.y];
            o[i].x = fmaf(fmaf(c.w, Bp.x, c.y), Ap.x, fmaf(c.z, Bp.x, c.x));
            o[i].y = fmaf(fmaf(c.w, Bp.y, c.y), Ap.y, fmaf(c.z, Bp.y, c.x));
        }
        __syncthreads();
#pragma unroll
        for (int i = 0; i < GPT; ++i) buf[tid + i * THREADS] = o[i];
        __syncthreads();
    }
    float a0 = 0.f, a1 = 0.f;
#pragma unroll
    for (int i = 0; i < GPT; ++i) {
        const int g = tid + i * THREADS;
        const float lw = lin_w[g];
        const float2 bv = buf[g];
        a0 = fmaf(bv.x, lw, a0);
        a1 = fmaf(bv.y, lw, a1);
    }
#pragma unroll
    for (int off = 32; off > 0; off >>= 1) {
        a0 += __shfl_down(a0, off);
        a1 += __shfl_down(a1, off);
    }
    const int lane = tid & 63, wid = tid >> 6;
    if (lane == 0) { red0[wid] = a0; red1[wid] = a1; }
    __syncthreads();
    if (tid == 0) {
        float s0 = 0.f, s1 = 0.f;
#pragma unroll
        for (int k = 0; k < THREADS / 64; ++k) { s0 += red0[k]; s1 += red1[k]; }
        const float lb = lin_b[0];
        out[row0]     = s0 + lb;
        out[row0 + 1] = s1 + lb;
    }
}

extern "C" void kernel_launch(void* const* d_in, const int* in_sizes, int n_in,
                              void* d_out, int out_size, void* d_ws, size_t ws_size,
                              hipStream_t stream) {
    // layout: [x, idx0, w0, idx1, w1, ..., idx5, w5, lin_w, lin_b]
    const float* x = (const float*)d_in[0];
    Ptrs P;
    for (int l = 0; l < NLAYER; ++l) {
        P.idx[l] = (const int*)d_in[1 + 2 * l];
        P.w[l]   = (const float*)d_in[2 + 2 * l];
    }
    const float* lin_w = (const float*)d_in[13];
    const float* lin_b = (const float*)d_in[14];
    float* out = (float*)d_out;

    const size_t coef_bytes = (size_t)NLAYER * G_DIM * sizeof(float4);
    const size_t sidx_bytes = (size_t)NLAYER * G_DIM * sizeof(unsigned);
    if (ws_size >= coef_bytes + sidx_bytes) {
        float4*   coef = (float4*)d_ws;
        unsigned* sidx = (unsigned*)((char*)d_ws + coef_bytes);
        dim3 cgrid(G_DIM / 256, NLAYER);
        pack_kernel<<<cgrid, 256, 0, stream>>>(P, coef, sidx);
        fused_ws_kernel<<<N_BATCH / ROWS_PER_BLOCK, THREADS, 0, stream>>>(
            x, coef, sidx, lin_w, lin_b, out);
    } else {
        fused_fallback_kernel<<<N_BATCH / ROWS_PER_BLOCK, THREADS, 0, stream>>>(
            x, P, lin_w, lin_b, out);
    }
}

// Round 6
// 157.514 us; speedup vs baseline: 1.5412x; 1.5412x over previous
//
#include <hip/hip_runtime.h>

#define G_DIM 16384
#define N_BATCH 2048
#define IN_DIM 1024
#define NLAYER 6
#define THREADS 1024
#define GPT 16                 // gates per thread
#define HALF 8                 // half-layer pipeline chunk
#define ROWS_PER_BLOCK 2

// Barrier that waits only on LDS ops: global (vmcnt) loads stay in flight
// across it. __syncthreads() would drain vmcnt(0) and kill the prefetch.
#define LDS_BARRIER() asm volatile("s_waitcnt lgkmcnt(0)\n\ts_barrier" ::: "memory")

struct Ptrs {
    const int*   idx[NLAYER];
    const float* w[NLAYER];
};

__device__ __forceinline__ float4 softmax_coef(const float* __restrict__ w, int g) {
    float v[16];
    float m = -1e30f;
#pragma unroll
    for (int k = 0; k < 16; ++k) { v[k] = w[k * G_DIM + g]; m = fmaxf(m, v[k]); }
    float s = 0.f;
#pragma unroll
    for (int k = 0; k < 16; ++k) { v[k] = expf(v[k] - m); s += v[k]; }
    const float inv = 1.f / s;
    float4 c;
    c.x = (v[8]+v[9]+v[10]+v[11]+v[12]+v[13]+v[14]+v[15]) * inv;
    c.y = (v[2]+v[3]+v[6]+v[7] - v[8]-v[9]-v[12]-v[13]) * inv;
    c.z = (v[4]+v[5]+v[6]+v[7] - v[8]-v[9]-v[10]-v[11]) * inv;
    c.w = (v[1]-v[2]-v[4]-2.f*v[6]-v[7]+v[8]+2.f*v[9]+v[11]+v[13]-v[14]) * inv;
    return c;
}

// ---- precompute: coef[l][g] (float4) and packed idx (lo16 = A, hi16 = B) ----
__global__ __launch_bounds__(256) void pack_kernel(Ptrs P, float4* __restrict__ coef,
                                                   unsigned* __restrict__ sidx) {
    const int g = blockIdx.x * blockDim.x + threadIdx.x;
    const int l = blockIdx.y;
    coef[(size_t)l * G_DIM + g] = softmax_coef(P.w[l], g);
    const int2 p = ((const int2*)P.idx[l])[g];
    sidx[(size_t)l * G_DIM + g] = (unsigned)p.x | ((unsigned)p.y << 16);
}

// per-gate gather + fma (buf must be the LDS array in scope -> ds_ addressing)
#define GATE_FMA(PK, C, O)                                                   \
    do {                                                                     \
        const unsigned pk_ = (PK);                                           \
        const float2 Ap_ = buf[pk_ & 0xFFFFu];                               \
        const float2 Bp_ = buf[pk_ >> 16];                                   \
        (O).x = fmaf(fmaf((C).w, Bp_.x, (C).y), Ap_.x, fmaf((C).z, Bp_.x, (C).x)); \
        (O).y = fmaf(fmaf((C).w, Bp_.y, (C).y), Ap_.y, fmaf((C).z, Bp_.y, (C).x)); \
    } while (0)

// ---- main fused kernel: 2 rows/block interleaved float2 in LDS.
//      Cross-layer software pipeline: next layer's idx + first coef half are
//      issued BEFORE the lgkm-only barriers and stay in flight across them. ----
__global__ __launch_bounds__(THREADS)
__attribute__((amdgpu_waves_per_eu(4, 4)))
void fused_ws_kernel(
    const float* __restrict__ x,
    const float4* __restrict__ coef,
    const unsigned* __restrict__ sidx,
    const float* __restrict__ lin_w,
    const float* __restrict__ lin_b,
    float* __restrict__ out)
{
    __shared__ float2 buf[G_DIM];            // 128 KB: .x = row0, .y = row1
    __shared__ float red0[THREADS / 64];
    __shared__ float red1[THREADS / 64];

    const int tid  = threadIdx.x;
    const int row0 = blockIdx.x * ROWS_PER_BLOCK;

    for (int i = tid; i < IN_DIM; i += THREADS) {
        buf[i] = make_float2(x[(size_t)row0 * IN_DIM + i],
                             x[(size_t)(row0 + 1) * IN_DIM + i]);
    }

    // layer-0 state: packed indices + low coef half (in flight while rows load)
    unsigned pa[GPT];
#pragma unroll
    for (int i = 0; i < GPT; ++i) pa[i] = sidx[tid + i * THREADS];
    float4 clo[HALF];
#pragma unroll
    for (int j = 0; j < HALF; ++j) clo[j] = coef[tid + j * THREADS];

    __syncthreads();   // rows staged (full drain OK here, once)

    float a0 = 0.f, a1 = 0.f;   // final dot accumulators

#pragma unroll
    for (int l = 0; l < NLAYER; ++l) {
        const float4* __restrict__ cl = coef + (size_t)l * G_DIM;

        // issue high coef half for THIS layer
        float4 chi[HALF];
#pragma unroll
        for (int j = 0; j < HALF; ++j) chi[j] = cl[tid + (HALF + j) * THREADS];

        float2 o[GPT];

        // gather+fma gates 0..7 with pre-loaded clo (hides chi latency)
#pragma unroll
        for (int j = 0; j < HALF; ++j) GATE_FMA(pa[j], clo[j], o[j]);

        // issue next layer's prefetch: packed idx + low coef half.
        // These survive the lgkm-only barriers below.
        unsigned pn[GPT];
        float4 cn[HALF];
        if (l + 1 < NLAYER) {
            const unsigned* __restrict__ sl = sidx + (size_t)(l + 1) * G_DIM;
            const float4*  __restrict__ cl2 = coef + (size_t)(l + 1) * G_DIM;
#pragma unroll
            for (int i = 0; i < GPT; ++i) pn[i] = sl[tid + i * THREADS];
#pragma unroll
            for (int j = 0; j < HALF; ++j) cn[j] = cl2[tid + j * THREADS];
        }

        // gather+fma gates 8..15 with chi
#pragma unroll
        for (int j = 0; j < HALF; ++j) GATE_FMA(pa[HALF + j], chi[j], o[HALF + j]);

        if (l + 1 < NLAYER) {
            LDS_BARRIER();     // all waves' ds_reads retired; vmem stays in flight
#pragma unroll
            for (int i = 0; i < GPT; ++i) buf[tid + i * THREADS] = o[i];
            LDS_BARRIER();     // layer fully materialized
#pragma unroll
            for (int i = 0; i < GPT; ++i) pa[i] = pn[i];
#pragma unroll
            for (int j = 0; j < HALF; ++j) clo[j] = cn[j];
        } else {
            // last layer: dot directly from registers, no write-back
#pragma unroll
            for (int i = 0; i < GPT; ++i) {
                const float lw = lin_w[tid + i * THREADS];
                a0 = fmaf(o[i].x, lw, a0);
                a1 = fmaf(o[i].y, lw, a1);
            }
        }
    }

    // cross-lane / cross-wave reduction
#pragma unroll
    for (int off = 32; off > 0; off >>= 1) {
        a0 += __shfl_down(a0, off);
        a1 += __shfl_down(a1, off);
    }
    const int lane = tid & 63, wid = tid >> 6;
    if (lane == 0) { red0[wid] = a0; red1[wid] = a1; }
    __syncthreads();
    if (tid == 0) {
        float s0 = 0.f, s1 = 0.f;
#pragma unroll
        for (int k = 0; k < THREADS / 64; ++k) { s0 += red0[k]; s1 += red1[k]; }
        const float lb = lin_b[0];
        out[row0]     = s0 + lb;
        out[row0 + 1] = s1 + lb;
    }
}

// ---- fallback (small ws): inline softmax, direct int2 idx (correctness only) ----
__global__ __launch_bounds__(THREADS, 1) void fused_fallback_kernel(
    const float* __restrict__ x, Ptrs P,
    const float* __restrict__ lin_w, const float* __restrict__ lin_b,
    float* __restrict__ out)
{
    __shared__ float2 buf[G_DIM];
    __shared__ float red0[THREADS / 64];
    __shared__ float red1[THREADS / 64];
    const int tid  = threadIdx.x;
    const int row0 = blockIdx.x * ROWS_PER_BLOCK;
    for (int i = tid; i < IN_DIM; i += THREADS)
        buf[i] = make_float2(x[(size_t)row0 * IN_DIM + i],
                             x[(size_t)(row0 + 1) * IN_DIM + i]);
    __syncthreads();
    float2 o[GPT];
    for (int l = 0; l < NLAYER; ++l) {
        const int2* __restrict__ idxl = (const int2*)P.idx[l];
#pragma unroll
        for (int i = 0; i < GPT; ++i) {
            const int g = tid + i * THREADS;
            const int2 p = idxl[g];
            const float4 c = softmax_coef(P.w[l], g);
            const float2 Ap = buf[p.x];
            const float2 Bp = buf[p.y];
            o[i].x = fmaf(fmaf(c.w, Bp.x, c.y), Ap.x, fmaf(c.z, Bp.x, c.x));
            o[i].y = fmaf(fmaf(c.w, Bp.y, c.y), Ap.y, fmaf(c.z, Bp.y, c.x));
        }
        __syncthreads();
#pragma unroll
        for (int i = 0; i < GPT; ++i) buf[tid + i * THREADS] = o[i];
        __syncthreads();
    }
    float a0 = 0.f, a1 = 0.f;
#pragma unroll
    for (int i = 0; i < GPT; ++i) {
        const int g = tid + i * THREADS;
        const float lw = lin_w[g];
        const float2 bv = buf[g];
        a0 = fmaf(bv.x, lw, a0);
        a1 = fmaf(bv.y, lw, a1);
    }
#pragma unroll
    for (int off = 32; off > 0; off >>= 1) {
        a0 += __shfl_down(a0, off);
        a1 += __shfl_down(a1, off);
    }
    const int lane = tid & 63, wid = tid >> 6;
    if (lane == 0) { red0[wid] = a0; red1[wid] = a1; }
    __syncthreads();
    if (tid == 0) {
        float s0 = 0.f, s1 = 0.f;
#pragma unroll
        for (int k = 0; k < THREADS / 64; ++k) { s0 += red0[k]; s1 += red1[k]; }
        const float lb = lin_b[0];
        out[row0]     = s0 + lb;
        out[row0 + 1] = s1 + lb;
    }
}

extern "C" void kernel_launch(void* const* d_in, const int* in_sizes, int n_in,
                              void* d_out, int out_size, void* d_ws, size_t ws_size,
                              hipStream_t stream) {
    // layout: [x, idx0, w0, idx1, w1, ..., idx5, w5, lin_w, lin_b]
    const float* x = (const float*)d_in[0];
    Ptrs P;
    for (int l = 0; l < NLAYER; ++l) {
        P.idx[l] = (const int*)d_in[1 + 2 * l];
        P.w[l]   = (const float*)d_in[2 + 2 * l];
    }
    const float* lin_w = (const float*)d_in[13];
    const float* lin_b = (const float*)d_in[14];
    float* out = (float*)d_out;

    const size_t coef_bytes = (size_t)NLAYER * G_DIM * sizeof(float4);
    const size_t sidx_bytes = (size_t)NLAYER * G_DIM * sizeof(unsigned);
    if (ws_size >= coef_bytes + sidx_bytes) {
        float4*   coef = (float4*)d_ws;
        unsigned* sidx = (unsigned*)((char*)d_ws + coef_bytes);
        dim3 cgrid(G_DIM / 256, NLAYER);
        pack_kernel<<<cgrid, 256, 0, stream>>>(P, coef, sidx);
        fused_ws_kernel<<<N_BATCH / ROWS_PER_BLOCK, THREADS, 0, stream>>>(
            x, coef, sidx, lin_w, lin_b, out);
    } else {
        fused_fallback_kernel<<<N_BATCH / ROWS_PER_BLOCK, THREADS, 0, stream>>>(
            x, P, lin_w, lin_b, out);
    }
}

// Round 7
// 89.012 us; speedup vs baseline: 2.7273x; 1.7696x over previous
//
#include <hip/hip_runtime.h>
#include <hip/hip_fp16.h>

#define G_DIM 16384
#define N_BATCH 2048
#define IN_DIM 1024
#define NLAYER 6
#define THREADS 1024
#define GPT 16                 // gates per thread
#define CHUNK 4
#define NCHUNK (GPT / CHUNK)
#define ROWS_PER_BLOCK 2

struct Ptrs {
    const int*   idx[NLAYER];
    const float* w[NLAYER];
};

__device__ __forceinline__ float4 softmax_coef(const float* __restrict__ w, int g) {
    float v[16];
    float m = -1e30f;
#pragma unroll
    for (int k = 0; k < 16; ++k) { v[k] = w[k * G_DIM + g]; m = fmaxf(m, v[k]); }
    float s = 0.f;
#pragma unroll
    for (int k = 0; k < 16; ++k) { v[k] = expf(v[k] - m); s += v[k]; }
    const float inv = 1.f / s;
    float4 c;
    c.x = (v[8]+v[9]+v[10]+v[11]+v[12]+v[13]+v[14]+v[15]) * inv;
    c.y = (v[2]+v[3]+v[6]+v[7] - v[8]-v[9]-v[12]-v[13]) * inv;
    c.z = (v[4]+v[5]+v[6]+v[7] - v[8]-v[9]-v[10]-v[11]) * inv;
    c.w = (v[1]-v[2]-v[4]-2.f*v[6]-v[7]+v[8]+2.f*v[9]+v[11]+v[13]-v[14]) * inv;
    return c;
}

// ---- precompute: coef[l][g] (float4) and packed idx (lo16 = A, hi16 = B) ----
__global__ __launch_bounds__(256) void pack_kernel(Ptrs P, float4* __restrict__ coef,
                                                   unsigned* __restrict__ sidx) {
    const int g = blockIdx.x * blockDim.x + threadIdx.x;
    const int l = blockIdx.y;
    coef[(size_t)l * G_DIM + g] = softmax_coef(P.w[l], g);
    const int2 p = ((const int2*)P.idx[l])[g];
    sidx[(size_t)l * G_DIM + g] = (unsigned)p.x | ((unsigned)p.y << 16);
}

// ---- main fused kernel: 2 rows/block packed as half2 in LDS (64 KB ->
//      2 blocks/CU co-resident; cross-block overlap replaces asm pipelining).
//      Compute in f32; activations rounded to f16 once per stored layer;
//      last layer never stored (fused into the lin_w dot). ----
__global__ __launch_bounds__(THREADS) void fused_ws_kernel(
    const float* __restrict__ x,
    const float4* __restrict__ coef,
    const unsigned* __restrict__ sidx,
    const float* __restrict__ lin_w,
    const float* __restrict__ lin_b,
    float* __restrict__ out)
{
    __shared__ __half2 buf[G_DIM];           // 64 KB: .x = row0, .y = row1
    __shared__ float red0[THREADS / 64];
    __shared__ float red1[THREADS / 64];

    const int tid  = threadIdx.x;
    const int row0 = blockIdx.x * ROWS_PER_BLOCK;

    for (int i = tid; i < IN_DIM; i += THREADS) {
        buf[i] = __floats2half2_rn(x[(size_t)row0 * IN_DIM + i],
                                   x[(size_t)(row0 + 1) * IN_DIM + i]);
    }

    // hoist layer-0 packed indices while rows load
    unsigned pa[GPT];
#pragma unroll
    for (int i = 0; i < GPT; ++i) pa[i] = sidx[tid + i * THREADS];

    __syncthreads();

    // ---- layers 0..NLAYER-2: gather -> f32 fma -> pack f16 -> write ----
#pragma unroll
    for (int l = 0; l < NLAYER - 1; ++l) {
        const float4* __restrict__ cl = coef + (size_t)l * G_DIM;
        __half2 opk[GPT];
        float4 c0[CHUNK], c1[CHUNK];

#pragma unroll
        for (int j = 0; j < CHUNK; ++j) c0[j] = cl[tid + j * THREADS];

#pragma unroll
        for (int ch = 0; ch < NCHUNK; ++ch) {
            if (ch + 1 < NCHUNK) {
#pragma unroll
                for (int j = 0; j < CHUNK; ++j) {
                    const float4 t = cl[tid + ((ch + 1) * CHUNK + j) * THREADS];
                    if (ch & 1) c0[j] = t; else c1[j] = t;
                }
            }
#pragma unroll
            for (int j = 0; j < CHUNK; ++j) {
                const int i = ch * CHUNK + j;
                const unsigned pk = pa[i];
                const float2 A = __half22float2(buf[pk & 0xFFFFu]);
                const float2 B = __half22float2(buf[pk >> 16]);
                const float4 c = (ch & 1) ? c1[j] : c0[j];
                const float ox = fmaf(fmaf(c.w, B.x, c.y), A.x, fmaf(c.z, B.x, c.x));
                const float oy = fmaf(fmaf(c.w, B.y, c.y), A.y, fmaf(c.z, B.y, c.x));
                opk[i] = __floats2half2_rn(ox, oy);
            }
        }

        // prefetch next layer's packed indices (hides under write phase)
        unsigned pn[GPT];
        {
            const unsigned* __restrict__ sl = sidx + (size_t)(l + 1) * G_DIM;
#pragma unroll
            for (int i = 0; i < GPT; ++i) pn[i] = sl[tid + i * THREADS];
        }

        __syncthreads();   // all reads of this layer done
#pragma unroll
        for (int i = 0; i < GPT; ++i) buf[tid + i * THREADS] = opk[i];
        __syncthreads();   // layer fully materialized
#pragma unroll
        for (int i = 0; i < GPT; ++i) pa[i] = pn[i];
    }

    // ---- last layer fused with the lin_w dot: outputs stay f32, never stored ----
    float a0 = 0.f, a1 = 0.f;
    {
        const float4* __restrict__ cl = coef + (size_t)(NLAYER - 1) * G_DIM;
        float4 c0[CHUNK], c1[CHUNK];
#pragma unroll
        for (int j = 0; j < CHUNK; ++j) c0[j] = cl[tid + j * THREADS];

#pragma unroll
        for (int ch = 0; ch < NCHUNK; ++ch) {
            if (ch + 1 < NCHUNK) {
#pragma unroll
                for (int j = 0; j < CHUNK; ++j) {
                    const float4 t = cl[tid + ((ch + 1) * CHUNK + j) * THREADS];
                    if (ch & 1) c0[j] = t; else c1[j] = t;
                }
            }
#pragma unroll
            for (int j = 0; j < CHUNK; ++j) {
                const int i = ch * CHUNK + j;
                const unsigned pk = pa[i];
                const float2 A = __half22float2(buf[pk & 0xFFFFu]);
                const float2 B = __half22float2(buf[pk >> 16]);
                const float4 c = (ch & 1) ? c1[j] : c0[j];
                const float ox = fmaf(fmaf(c.w, B.x, c.y), A.x, fmaf(c.z, B.x, c.x));
                const float oy = fmaf(fmaf(c.w, B.y, c.y), A.y, fmaf(c.z, B.y, c.x));
                const float lw = lin_w[tid + i * THREADS];
                a0 = fmaf(ox, lw, a0);
                a1 = fmaf(oy, lw, a1);
            }
        }
    }

    // cross-lane / cross-wave reduction
#pragma unroll
    for (int off = 32; off > 0; off >>= 1) {
        a0 += __shfl_down(a0, off);
        a1 += __shfl_down(a1, off);
    }
    const int lane = tid & 63, wid = tid >> 6;
    if (lane == 0) { red0[wid] = a0; red1[wid] = a1; }
    __syncthreads();
    if (tid == 0) {
        float s0 = 0.f, s1 = 0.f;
#pragma unroll
        for (int k = 0; k < THREADS / 64; ++k) { s0 += red0[k]; s1 += red1[k]; }
        const float lb = lin_b[0];
        out[row0]     = s0 + lb;
        out[row0 + 1] = s1 + lb;
    }
}

// ---- fallback (small ws): exact f32, inline softmax (correctness only) ----
__global__ __launch_bounds__(THREADS, 1) void fused_fallback_kernel(
    const float* __restrict__ x, Ptrs P,
    const float* __restrict__ lin_w, const float* __restrict__ lin_b,
    float* __restrict__ out)
{
    __shared__ float2 buf[G_DIM];
    __shared__ float red0[THREADS / 64];
    __shared__ float red1[THREADS / 64];
    const int tid  = threadIdx.x;
    const int row0 = blockIdx.x * ROWS_PER_BLOCK;
    for (int i = tid; i < IN_DIM; i += THREADS)
        buf[i] = make_float2(x[(size_t)row0 * IN_DIM + i],
                             x[(size_t)(row0 + 1) * IN_DIM + i]);
    __syncthreads();
    float2 o[GPT];
    for (int l = 0; l < NLAYER; ++l) {
        const int2* __restrict__ idxl = (const int2*)P.idx[l];
#pragma unroll
        for (int i = 0; i < GPT; ++i) {
            const int g = tid + i * THREADS;
            const int2 p = idxl[g];
            const float4 c = softmax_coef(P.w[l], g);
            const float2 Ap = buf[p.x];
            const float2 Bp = buf[p.y];
            o[i].x = fmaf(fmaf(c.w, Bp.x, c.y), Ap.x, fmaf(c.z, Bp.x, c.x));
            o[i].y = fmaf(fmaf(c.w, Bp.y, c.y), Ap.y, fmaf(c.z, Bp.y, c.x));
        }
        __syncthreads();
#pragma unroll
        for (int i = 0; i < GPT; ++i) buf[tid + i * THREADS] = o[i];
        __syncthreads();
    }
    float a0 = 0.f, a1 = 0.f;
#pragma unroll
    for (int i = 0; i < GPT; ++i) {
        const int g = tid + i * THREADS;
        const float lw = lin_w[g];
        const float2 bv = buf[g];
        a0 = fmaf(bv.x, lw, a0);
        a1 = fmaf(bv.y, lw, a1);
    }
#pragma unroll
    for (int off = 32; off > 0; off >>= 1) {
        a0 += __shfl_down(a0, off);
        a1 += __shfl_down(a1, off);
    }
    const int lane = tid & 63, wid = tid >> 6;
    if (lane == 0) { red0[wid] = a0; red1[wid] = a1; }
    __syncthreads();
    if (tid == 0) {
        float s0 = 0.f, s1 = 0.f;
#pragma unroll
        for (int k = 0; k < THREADS / 64; ++k) { s0 += red0[k]; s1 += red1[k]; }
        const float lb = lin_b[0];
        out[row0]     = s0 + lb;
        out[row0 + 1] = s1 + lb;
    }
}

extern "C" void kernel_launch(void* const* d_in, const int* in_sizes, int n_in,
                              void* d_out, int out_size, void* d_ws, size_t ws_size,
                              hipStream_t stream) {
    // layout: [x, idx0, w0, idx1, w1, ..., idx5, w5, lin_w, lin_b]
    const float* x = (const float*)d_in[0];
    Ptrs P;
    for (int l = 0; l < NLAYER; ++l) {
        P.idx[l] = (const int*)d_in[1 + 2 * l];
        P.w[l]   = (const float*)d_in[2 + 2 * l];
    }
    const float* lin_w = (const float*)d_in[13];
    const float* lin_b = (const float*)d_in[14];
    float* out = (float*)d_out;

    const size_t coef_bytes = (size_t)NLAYER * G_DIM * sizeof(float4);
    const size_t sidx_bytes = (size_t)NLAYER * G_DIM * sizeof(unsigned);
    if (ws_size >= coef_bytes + sidx_bytes) {
        float4*   coef = (float4*)d_ws;
        unsigned* sidx = (unsigned*)((char*)d_ws + coef_bytes);
        dim3 cgrid(G_DIM / 256, NLAYER);
        pack_kernel<<<cgrid, 256, 0, stream>>>(P, coef, sidx);
        fused_ws_kernel<<<N_BATCH / ROWS_PER_BLOCK, THREADS, 0, stream>>>(
            x, coef, sidx, lin_w, lin_b, out);
    } else {
        fused_fallback_kernel<<<N_BATCH / ROWS_PER_BLOCK, THREADS, 0, stream>>>(
            x, P, lin_w, lin_b, out);
    }
}

// Round 8
// 63.884 us; speedup vs baseline: 3.8001x; 1.3933x over previous
//
#include <hip/hip_runtime.h>
#include <hip/hip_fp16.h>

#define G_DIM 16384
#define N_BATCH 2048
#define IN_DIM 1024
#define NLAYER 6
#define THREADS 1024
#define GPT 16                 // gates per thread
#define CHUNK 4
#define NCHUNK (GPT / CHUNK)
#define ROWS 4                 // batch rows per block

struct Ptrs {
    const int*   idx[NLAYER];
    const float* w[NLAYER];
};

__device__ __forceinline__ float2 h2f(unsigned u) {
    __half2 h; *reinterpret_cast<unsigned*>(&h) = u;
    return __half22float2(h);
}
__device__ __forceinline__ unsigned f2h(float a, float b) {
    __half2 h = __floats2half2_rn(a, b);
    return *reinterpret_cast<unsigned*>(&h);
}

__device__ __forceinline__ float4 softmax_coef(const float* __restrict__ w, int g) {
    float v[16];
    float m = -1e30f;
#pragma unroll
    for (int k = 0; k < 16; ++k) { v[k] = w[k * G_DIM + g]; m = fmaxf(m, v[k]); }
    float s = 0.f;
#pragma unroll
    for (int k = 0; k < 16; ++k) { v[k] = expf(v[k] - m); s += v[k]; }
    const float inv = 1.f / s;
    float4 c;
    c.x = (v[8]+v[9]+v[10]+v[11]+v[12]+v[13]+v[14]+v[15]) * inv;
    c.y = (v[2]+v[3]+v[6]+v[7] - v[8]-v[9]-v[12]-v[13]) * inv;
    c.z = (v[4]+v[5]+v[6]+v[7] - v[8]-v[9]-v[10]-v[11]) * inv;
    c.w = (v[1]-v[2]-v[4]-2.f*v[6]-v[7]+v[8]+2.f*v[9]+v[11]+v[13]-v[14]) * inv;
    return c;
}

// ---- precompute: coef[l][g] (float4) and packed idx (lo16 = A, hi16 = B) ----
__global__ __launch_bounds__(256) void pack_kernel(Ptrs P, float4* __restrict__ coef,
                                                   unsigned* __restrict__ sidx) {
    const int g = blockIdx.x * blockDim.x + threadIdx.x;
    const int l = blockIdx.y;
    coef[(size_t)l * G_DIM + g] = softmax_coef(P.w[l], g);
    const int2 p = ((const int2*)P.idx[l])[g];
    sidx[(size_t)l * G_DIM + g] = (unsigned)p.x | ((unsigned)p.y << 16);
}

// ---- main fused kernel: 4 batch rows per block as uint2{half2,half2} in LDS.
//      One b64 gather serves 4 rows; coef/idx L2 stream amortized over 4 rows. ----
__global__ __launch_bounds__(THREADS) void fused_ws_kernel(
    const float* __restrict__ x,
    const float4* __restrict__ coef,
    const unsigned* __restrict__ sidx,
    const float* __restrict__ lin_w,
    const float* __restrict__ lin_b,
    float* __restrict__ out)
{
    __shared__ uint2 buf[G_DIM];             // 128 KB: {h2(r0,r1), h2(r2,r3)}
    __shared__ float red[ROWS][THREADS / 64];

    const int tid  = threadIdx.x;
    const int row0 = blockIdx.x * ROWS;

    for (int i = tid; i < IN_DIM; i += THREADS) {
        const float r0 = x[(size_t)(row0 + 0) * IN_DIM + i];
        const float r1 = x[(size_t)(row0 + 1) * IN_DIM + i];
        const float r2 = x[(size_t)(row0 + 2) * IN_DIM + i];
        const float r3 = x[(size_t)(row0 + 3) * IN_DIM + i];
        buf[i] = make_uint2(f2h(r0, r1), f2h(r2, r3));
    }
    __syncthreads();

    // ---- layers 0..NLAYER-2: gather -> f32 fma -> pack f16 -> write ----
    for (int l = 0; l < NLAYER - 1; ++l) {
        const float4*   __restrict__ cl = coef + (size_t)l * G_DIM;
        const unsigned* __restrict__ sl = sidx + (size_t)l * G_DIM;
        uint2 o[GPT];

#pragma unroll
        for (int ch = 0; ch < NCHUNK; ++ch) {
            unsigned pk[CHUNK];
            float4   c[CHUNK];
#pragma unroll
            for (int j = 0; j < CHUNK; ++j) {
                pk[j] = sl[tid + (ch * CHUNK + j) * THREADS];
                c[j]  = cl[tid + (ch * CHUNK + j) * THREADS];
            }
#pragma unroll
            for (int j = 0; j < CHUNK; ++j) {
                const uint2 Au = buf[pk[j] & 0xFFFFu];
                const uint2 Bu = buf[pk[j] >> 16];
                const float2 A01 = h2f(Au.x), A23 = h2f(Au.y);
                const float2 B01 = h2f(Bu.x), B23 = h2f(Bu.y);
                const float4 cc = c[j];
                const float o0 = fmaf(fmaf(cc.w, B01.x, cc.y), A01.x, fmaf(cc.z, B01.x, cc.x));
                const float o1 = fmaf(fmaf(cc.w, B01.y, cc.y), A01.y, fmaf(cc.z, B01.y, cc.x));
                const float o2 = fmaf(fmaf(cc.w, B23.x, cc.y), A23.x, fmaf(cc.z, B23.x, cc.x));
                const float o3 = fmaf(fmaf(cc.w, B23.y, cc.y), A23.y, fmaf(cc.z, B23.y, cc.x));
                o[ch * CHUNK + j] = make_uint2(f2h(o0, o1), f2h(o2, o3));
            }
        }

        __syncthreads();   // all reads of this layer done
#pragma unroll
        for (int i = 0; i < GPT; ++i) buf[tid + i * THREADS] = o[i];
        __syncthreads();   // layer fully materialized
    }

    // ---- last layer fused with the lin_w dot: outputs stay f32, never stored ----
    float a0 = 0.f, a1 = 0.f, a2 = 0.f, a3 = 0.f;
    {
        const float4*   __restrict__ cl = coef + (size_t)(NLAYER - 1) * G_DIM;
        const unsigned* __restrict__ sl = sidx + (size_t)(NLAYER - 1) * G_DIM;
#pragma unroll
        for (int ch = 0; ch < NCHUNK; ++ch) {
            unsigned pk[CHUNK];
            float4   c[CHUNK];
            float    lw[CHUNK];
#pragma unroll
            for (int j = 0; j < CHUNK; ++j) {
                pk[j] = sl[tid + (ch * CHUNK + j) * THREADS];
                c[j]  = cl[tid + (ch * CHUNK + j) * THREADS];
                lw[j] = lin_w[tid + (ch * CHUNK + j) * THREADS];
            }
#pragma unroll
            for (int j = 0; j < CHUNK; ++j) {
                const uint2 Au = buf[pk[j] & 0xFFFFu];
                const uint2 Bu = buf[pk[j] >> 16];
                const float2 A01 = h2f(Au.x), A23 = h2f(Au.y);
                const float2 B01 = h2f(Bu.x), B23 = h2f(Bu.y);
                const float4 cc = c[j];
                a0 = fmaf(fmaf(fmaf(cc.w, B01.x, cc.y), A01.x, fmaf(cc.z, B01.x, cc.x)), lw[j], a0);
                a1 = fmaf(fmaf(fmaf(cc.w, B01.y, cc.y), A01.y, fmaf(cc.z, B01.y, cc.x)), lw[j], a1);
                a2 = fmaf(fmaf(fmaf(cc.w, B23.x, cc.y), A23.x, fmaf(cc.z, B23.x, cc.x)), lw[j], a2);
                a3 = fmaf(fmaf(fmaf(cc.w, B23.y, cc.y), A23.y, fmaf(cc.z, B23.y, cc.x)), lw[j], a3);
            }
        }
    }

    // cross-lane / cross-wave reduction (4 rows)
#pragma unroll
    for (int off = 32; off > 0; off >>= 1) {
        a0 += __shfl_down(a0, off);
        a1 += __shfl_down(a1, off);
        a2 += __shfl_down(a2, off);
        a3 += __shfl_down(a3, off);
    }
    const int lane = tid & 63, wid = tid >> 6;
    if (lane == 0) { red[0][wid] = a0; red[1][wid] = a1; red[2][wid] = a2; red[3][wid] = a3; }
    __syncthreads();
    if (tid < ROWS) {
        float s = 0.f;
#pragma unroll
        for (int k = 0; k < THREADS / 64; ++k) s += red[tid][k];
        out[row0 + tid] = s + lin_b[0];
    }
}

// ---- fallback (small ws): exact f32, inline softmax (correctness only) ----
__global__ __launch_bounds__(THREADS, 1) void fused_fallback_kernel(
    const float* __restrict__ x, Ptrs P,
    const float* __restrict__ lin_w, const float* __restrict__ lin_b,
    float* __restrict__ out)
{
    __shared__ float2 buf[G_DIM];
    __shared__ float red0[THREADS / 64];
    __shared__ float red1[THREADS / 64];
    const int tid  = threadIdx.x;
    const int row0 = blockIdx.x * 2;
    for (int i = tid; i < IN_DIM; i += THREADS)
        buf[i] = make_float2(x[(size_t)row0 * IN_DIM + i],
                             x[(size_t)(row0 + 1) * IN_DIM + i]);
    __syncthreads();
    float2 o[GPT];
    for (int l = 0; l < NLAYER; ++l) {
        const int2* __restrict__ idxl = (const int2*)P.idx[l];
#pragma unroll
        for (int i = 0; i < GPT; ++i) {
            const int g = tid + i * THREADS;
            const int2 p = idxl[g];
            const float4 c = softmax_coef(P.w[l], g);
            const float2 Ap = buf[p.x];
            const float2 Bp = buf[p.y];
            o[i].x = fmaf(fmaf(c.w, Bp.x, c.y), Ap.x, fmaf(c.z, Bp.x, c.x));
            o[i].y = fmaf(fmaf(c.w, Bp.y, c.y), Ap.y, fmaf(c.z, Bp.y, c.x));
        }
        __syncthreads();
#pragma unroll
        for (int i = 0; i < GPT; ++i) buf[tid + i * THREADS] = o[i];
        __syncthreads();
    }
    float a0 = 0.f, a1 = 0.f;
#pragma unroll
    for (int i = 0; i < GPT; ++i) {
        const int g = tid + i * THREADS;
        const float lw = lin_w[g];
        const float2 bv = buf[g];
        a0 = fmaf(bv.x, lw, a0);
        a1 = fmaf(bv.y, lw, a1);
    }
#pragma unroll
    for (int off = 32; off > 0; off >>= 1) {
        a0 += __shfl_down(a0, off);
        a1 += __shfl_down(a1, off);
    }
    const int lane = tid & 63, wid = tid >> 6;
    if (lane == 0) { red0[wid] = a0; red1[wid] = a1; }
    __syncthreads();
    if (tid == 0) {
        float s0 = 0.f, s1 = 0.f;
#pragma unroll
        for (int k = 0; k < THREADS / 64; ++k) { s0 += red0[k]; s1 += red1[k]; }
        const float lb = lin_b[0];
        out[row0]     = s0 + lb;
        out[row0 + 1] = s1 + lb;
    }
}

extern "C" void kernel_launch(void* const* d_in, const int* in_sizes, int n_in,
                              void* d_out, int out_size, void* d_ws, size_t ws_size,
                              hipStream_t stream) {
    // layout: [x, idx0, w0, idx1, w1, ..., idx5, w5, lin_w, lin_b]
    const float* x = (const float*)d_in[0];
    Ptrs P;
    for (int l = 0; l < NLAYER; ++l) {
        P.idx[l] = (const int*)d_in[1 + 2 * l];
        P.w[l]   = (const float*)d_in[2 + 2 * l];
    }
    const float* lin_w = (const float*)d_in[13];
    const float* lin_b = (const float*)d_in[14];
    float* out = (float*)d_out;

    const size_t coef_bytes = (size_t)NLAYER * G_DIM * sizeof(float4);
    const size_t sidx_bytes = (size_t)NLAYER * G_DIM * sizeof(unsigned);
    if (ws_size >= coef_bytes + sidx_bytes) {
        float4*   coef = (float4*)d_ws;
        unsigned* sidx = (unsigned*)((char*)d_ws + coef_bytes);
        dim3 cgrid(G_DIM / 256, NLAYER);
        pack_kernel<<<cgrid, 256, 0, stream>>>(P, coef, sidx);
        fused_ws_kernel<<<N_BATCH / ROWS, THREADS, 0, stream>>>(
            x, coef, sidx, lin_w, lin_b, out);
    } else {
        fused_fallback_kernel<<<N_BATCH / 2, THREADS, 0, stream>>>(
            x, P, lin_w, lin_b, out);
    }
}

// Round 9
// 60.771 us; speedup vs baseline: 3.9948x; 1.0512x over previous
//
#include <hip/hip_runtime.h>
#include <hip/hip_fp16.h>

#define G_DIM 16384
#define N_BATCH 2048
#define IN_DIM 1024
#define NLAYER 6
#define THREADS 1024
#define GPT 16                 // gates per thread
#define CHUNK 4
#define NCHUNK (GPT / CHUNK)
#define ROWS 4                 // batch rows per block

struct Ptrs {
    const int*   idx[NLAYER];
    const float* w[NLAYER];
};

__device__ __forceinline__ float2 h2f(unsigned u) {
    __half2 h; *reinterpret_cast<unsigned*>(&h) = u;
    return __half22float2(h);
}
__device__ __forceinline__ unsigned f2h(float a, float b) {
    __half2 h = __floats2half2_rn(a, b);
    return *reinterpret_cast<unsigned*>(&h);
}

__device__ __forceinline__ float4 softmax_coef(const float* __restrict__ w, int g) {
    float v[16];
    float m = -1e30f;
#pragma unroll
    for (int k = 0; k < 16; ++k) { v[k] = w[k * G_DIM + g]; m = fmaxf(m, v[k]); }
    float s = 0.f;
#pragma unroll
    for (int k = 0; k < 16; ++k) { v[k] = expf(v[k] - m); s += v[k]; }
    const float inv = 1.f / s;
    float4 c;
    c.x = (v[8]+v[9]+v[10]+v[11]+v[12]+v[13]+v[14]+v[15]) * inv;
    c.y = (v[2]+v[3]+v[6]+v[7] - v[8]-v[9]-v[12]-v[13]) * inv;
    c.z = (v[4]+v[5]+v[6]+v[7] - v[8]-v[9]-v[10]-v[11]) * inv;
    c.w = (v[1]-v[2]-v[4]-2.f*v[6]-v[7]+v[8]+2.f*v[9]+v[11]+v[13]-v[14]) * inv;
    return c;
}

// ---- precompute: coef[l][g] (float4) and packed idx (lo16 = A, hi16 = B) ----
__global__ __launch_bounds__(256) void pack_kernel(Ptrs P, float4* __restrict__ coef,
                                                   unsigned* __restrict__ sidx) {
    const int g = blockIdx.x * blockDim.x + threadIdx.x;
    const int l = blockIdx.y;
    coef[(size_t)l * G_DIM + g] = softmax_coef(P.w[l], g);
    const int2 p = ((const int2*)P.idx[l])[g];
    sidx[(size_t)l * G_DIM + g] = (unsigned)p.x | ((unsigned)p.y << 16);
}

// ---- main fused kernel: 4 batch rows per block as uint2{half2,half2} in LDS.
//      idx stream software-pipelined one chunk ahead (crosses layer
//      boundaries), so gathers start without waiting on L2 latency. ----
__global__ __launch_bounds__(THREADS) void fused_ws_kernel(
    const float* __restrict__ x,
    const float4* __restrict__ coef,
    const unsigned* __restrict__ sidx,
    const float* __restrict__ lin_w,
    const float* __restrict__ lin_b,
    float* __restrict__ out)
{
    __shared__ uint2 buf[G_DIM];             // 128 KB: {h2(r0,r1), h2(r2,r3)}
    __shared__ float red[ROWS][THREADS / 64];

    const int tid  = threadIdx.x;
    const int row0 = blockIdx.x * ROWS;

#pragma unroll
    for (int i = tid; i < IN_DIM; i += THREADS) {
        const float r0 = x[(size_t)(row0 + 0) * IN_DIM + i];
        const float r1 = x[(size_t)(row0 + 1) * IN_DIM + i];
        const float r2 = x[(size_t)(row0 + 2) * IN_DIM + i];
        const float r3 = x[(size_t)(row0 + 3) * IN_DIM + i];
        buf[i] = make_uint2(f2h(r0, r1), f2h(r2, r3));
    }

    // prologue: layer-0 chunk-0 idx in flight while rows stage
    unsigned pk[CHUNK];
#pragma unroll
    for (int j = 0; j < CHUNK; ++j) pk[j] = sidx[tid + j * THREADS];

    __syncthreads();

    float a0 = 0.f, a1 = 0.f, a2 = 0.f, a3 = 0.f;

#pragma unroll
    for (int l = 0; l < NLAYER; ++l) {
        const float4*   __restrict__ cl = coef + (size_t)l * G_DIM;
        const unsigned* __restrict__ sl = sidx + (size_t)l * G_DIM;
        uint2 o[GPT];                        // dead (DCE'd) for the last layer

#pragma unroll
        for (int ch = 0; ch < NCHUNK; ++ch) {
            // issue NEXT chunk's idx (next layer's chunk 0 at layer tail)
            unsigned pkn[CHUNK];
            if (ch + 1 < NCHUNK) {
#pragma unroll
                for (int j = 0; j < CHUNK; ++j)
                    pkn[j] = sl[tid + ((ch + 1) * CHUNK + j) * THREADS];
            } else if (l + 1 < NLAYER) {
                const unsigned* __restrict__ sn = sidx + (size_t)(l + 1) * G_DIM;
#pragma unroll
                for (int j = 0; j < CHUNK; ++j)
                    pkn[j] = sn[tid + j * THREADS];
            }

            // current chunk's coef (+ lin_w on the last layer)
            float4 c[CHUNK];
#pragma unroll
            for (int j = 0; j < CHUNK; ++j)
                c[j] = cl[tid + (ch * CHUNK + j) * THREADS];
            float lw[CHUNK];
            if (l == NLAYER - 1) {
#pragma unroll
                for (int j = 0; j < CHUNK; ++j)
                    lw[j] = lin_w[tid + (ch * CHUNK + j) * THREADS];
            }

            // gather + fma (idx already resident -> ds_reads issue immediately)
#pragma unroll
            for (int j = 0; j < CHUNK; ++j) {
                const uint2 Au = buf[pk[j] & 0xFFFFu];
                const uint2 Bu = buf[pk[j] >> 16];
                const float2 A01 = h2f(Au.x), A23 = h2f(Au.y);
                const float2 B01 = h2f(Bu.x), B23 = h2f(Bu.y);
                const float4 cc = c[j];
                const float o0 = fmaf(fmaf(cc.w, B01.x, cc.y), A01.x, fmaf(cc.z, B01.x, cc.x));
                const float o1 = fmaf(fmaf(cc.w, B01.y, cc.y), A01.y, fmaf(cc.z, B01.y, cc.x));
                const float o2 = fmaf(fmaf(cc.w, B23.x, cc.y), A23.x, fmaf(cc.z, B23.x, cc.x));
                const float o3 = fmaf(fmaf(cc.w, B23.y, cc.y), A23.y, fmaf(cc.z, B23.y, cc.x));
                if (l < NLAYER - 1) {
                    o[ch * CHUNK + j] = make_uint2(f2h(o0, o1), f2h(o2, o3));
                } else {
                    a0 = fmaf(o0, lw[j], a0);
                    a1 = fmaf(o1, lw[j], a1);
                    a2 = fmaf(o2, lw[j], a2);
                    a3 = fmaf(o3, lw[j], a3);
                }
            }

            // rotate pipeline register
            if (ch + 1 < NCHUNK || l + 1 < NLAYER) {
#pragma unroll
                for (int j = 0; j < CHUNK; ++j) pk[j] = pkn[j];
            }
        }

        if (l < NLAYER - 1) {
            __syncthreads();   // all reads of this layer done
#pragma unroll
            for (int i = 0; i < GPT; ++i) buf[tid + i * THREADS] = o[i];
            __syncthreads();   // layer fully materialized
        }
    }

    // cross-lane / cross-wave reduction (4 rows)
#pragma unroll
    for (int off = 32; off > 0; off >>= 1) {
        a0 += __shfl_down(a0, off);
        a1 += __shfl_down(a1, off);
        a2 += __shfl_down(a2, off);
        a3 += __shfl_down(a3, off);
    }
    const int lane = tid & 63, wid = tid >> 6;
    if (lane == 0) { red[0][wid] = a0; red[1][wid] = a1; red[2][wid] = a2; red[3][wid] = a3; }
    __syncthreads();
    if (tid < ROWS) {
        float s = 0.f;
#pragma unroll
        for (int k = 0; k < THREADS / 64; ++k) s += red[tid][k];
        out[row0 + tid] = s + lin_b[0];
    }
}

// ---- fallback (small ws): exact f32, inline softmax (correctness only) ----
__global__ __launch_bounds__(THREADS, 1) void fused_fallback_kernel(
    const float* __restrict__ x, Ptrs P,
    const float* __restrict__ lin_w, const float* __restrict__ lin_b,
    float* __restrict__ out)
{
    __shared__ float2 buf[G_DIM];
    __shared__ float red0[THREADS / 64];
    __shared__ float red1[THREADS / 64];
    const int tid  = threadIdx.x;
    const int row0 = blockIdx.x * 2;
    for (int i = tid; i < IN_DIM; i += THREADS)
        buf[i] = make_float2(x[(size_t)row0 * IN_DIM + i],
                             x[(size_t)(row0 + 1) * IN_DIM + i]);
    __syncthreads();
    float2 o[GPT];
    for (int l = 0; l < NLAYER; ++l) {
        const int2* __restrict__ idxl = (const int2*)P.idx[l];
#pragma unroll
        for (int i = 0; i < GPT; ++i) {
            const int g = tid + i * THREADS;
            const int2 p = idxl[g];
            const float4 c = softmax_coef(P.w[l], g);
            const float2 Ap = buf[p.x];
            const float2 Bp = buf[p.y];
            o[i].x = fmaf(fmaf(c.w, Bp.x, c.y), Ap.x, fmaf(c.z, Bp.x, c.x));
            o[i].y = fmaf(fmaf(c.w, Bp.y, c.y), Ap.y, fmaf(c.z, Bp.y, c.x));
        }
        __syncthreads();
#pragma unroll
        for (int i = 0; i < GPT; ++i) buf[tid + i * THREADS] = o[i];
        __syncthreads();
    }
    float a0 = 0.f, a1 = 0.f;
#pragma unroll
    for (int i = 0; i < GPT; ++i) {
        const int g = tid + i * THREADS;
        const float lw = lin_w[g];
        const float2 bv = buf[g];
        a0 = fmaf(bv.x, lw, a0);
        a1 = fmaf(bv.y, lw, a1);
    }
#pragma unroll
    for (int off = 32; off > 0; off >>= 1) {
        a0 += __shfl_down(a0, off);
        a1 += __shfl_down(a1, off);
    }
    const int lane = tid & 63, wid = tid >> 6;
    if (lane == 0) { red0[wid] = a0; red1[wid] = a1; }
    __syncthreads();
    if (tid == 0) {
        float s0 = 0.f, s1 = 0.f;
#pragma unroll
        for (int k = 0; k < THREADS / 64; ++k) { s0 += red0[k]; s1 += red1[k]; }
        const float lb = lin_b[0];
        out[row0]     = s0 + lb;
        out[row0 + 1] = s1 + lb;
    }
}

extern "C" void kernel_launch(void* const* d_in, const int* in_sizes, int n_in,
                              void* d_out, int out_size, void* d_ws, size_t ws_size,
                              hipStream_t stream) {
    // layout: [x, idx0, w0, idx1, w1, ..., idx5, w5, lin_w, lin_b]
    const float* x = (const float*)d_in[0];
    Ptrs P;
    for (int l = 0; l < NLAYER; ++l) {
        P.idx[l] = (const int*)d_in[1 + 2 * l];
        P.w[l]   = (const float*)d_in[2 + 2 * l];
    }
    const float* lin_w = (const float*)d_in[13];
    const float* lin_b = (const float*)d_in[14];
    float* out = (float*)d_out;

    const size_t coef_bytes = (size_t)NLAYER * G_DIM * sizeof(float4);
    const size_t sidx_bytes = (size_t)NLAYER * G_DIM * sizeof(unsigned);
    if (ws_size >= coef_bytes + sidx_bytes) {
        float4*   coef = (float4*)d_ws;
        unsigned* sidx = (unsigned*)((char*)d_ws + coef_bytes);
        dim3 cgrid(G_DIM / 256, NLAYER);
        pack_kernel<<<cgrid, 256, 0, stream>>>(P, coef, sidx);
        fused_ws_kernel<<<N_BATCH / ROWS, THREADS, 0, stream>>>(
            x, coef, sidx, lin_w, lin_b, out);
    } else {
        fused_fallback_kernel<<<N_BATCH / 2, THREADS, 0, stream>>>(
            x, P, lin_w, lin_b, out);
    }
}

// Round 10
// 58.487 us; speedup vs baseline: 4.1508x; 1.0391x over previous
//
#include <hip/hip_runtime.h>
#include <hip/hip_fp16.h>

#define G_DIM 16384
#define N_BATCH 2048
#define IN_DIM 1024
#define NLAYER 6
#define THREADS 1024
#define GPT 16                 // gates per thread
#define CHUNK 4
#define NCHUNK (GPT / CHUNK)
#define ROWS 4                 // batch rows per block

struct Ptrs {
    const int*   idx[NLAYER];
    const float* w[NLAYER];
};

__device__ __forceinline__ float2 h2f(unsigned u) {
    __half2 h; *reinterpret_cast<unsigned*>(&h) = u;
    return __half22float2(h);
}
__device__ __forceinline__ unsigned f2h(float a, float b) {
    __half2 h = __floats2half2_rn(a, b);
    return *reinterpret_cast<unsigned*>(&h);
}

__device__ __forceinline__ float4 softmax_coef(const float* __restrict__ w, int g) {
    float v[16];
    float m = -1e30f;
#pragma unroll
    for (int k = 0; k < 16; ++k) { v[k] = w[k * G_DIM + g]; m = fmaxf(m, v[k]); }
    float s = 0.f;
#pragma unroll
    for (int k = 0; k < 16; ++k) { v[k] = expf(v[k] - m); s += v[k]; }
    const float inv = 1.f / s;
    float4 c;
    c.x = (v[8]+v[9]+v[10]+v[11]+v[12]+v[13]+v[14]+v[15]) * inv;
    c.y = (v[2]+v[3]+v[6]+v[7] - v[8]-v[9]-v[12]-v[13]) * inv;
    c.z = (v[4]+v[5]+v[6]+v[7] - v[8]-v[9]-v[10]-v[11]) * inv;
    c.w = (v[1]-v[2]-v[4]-2.f*v[6]-v[7]+v[8]+2.f*v[9]+v[11]+v[13]-v[14]) * inv;
    return c;
}

// ---- precompute: coef[l][g] as half4 (uint2) and packed idx (lo16=A, hi16=B) ----
__global__ __launch_bounds__(256) void pack_kernel(Ptrs P, uint2* __restrict__ hcf,
                                                   unsigned* __restrict__ sidx) {
    const int g = blockIdx.x * blockDim.x + threadIdx.x;
    const int l = blockIdx.y;
    const float4 c = softmax_coef(P.w[l], g);
    hcf[(size_t)l * G_DIM + g] = make_uint2(f2h(c.x, c.y), f2h(c.z, c.w));
    const int2 p = ((const int2*)P.idx[l])[g];
    sidx[(size_t)l * G_DIM + g] = (unsigned)p.x | ((unsigned)p.y << 16);
}

// ---- main fused kernel: 4 batch rows per block as uint2{half2,half2} in LDS.
//      idx AND half4-coef streams software-pipelined one chunk ahead
//      (crossing layer boundaries); compute stays f32. ----
__global__ __launch_bounds__(THREADS) void fused_ws_kernel(
    const float* __restrict__ x,
    const uint2* __restrict__ hcf,
    const unsigned* __restrict__ sidx,
    const float* __restrict__ lin_w,
    const float* __restrict__ lin_b,
    float* __restrict__ out)
{
    __shared__ uint2 buf[G_DIM];             // 128 KB: {h2(r0,r1), h2(r2,r3)}
    __shared__ float red[ROWS][THREADS / 64];

    const int tid  = threadIdx.x;
    const int row0 = blockIdx.x * ROWS;

#pragma unroll
    for (int i = tid; i < IN_DIM; i += THREADS) {
        const float r0 = x[(size_t)(row0 + 0) * IN_DIM + i];
        const float r1 = x[(size_t)(row0 + 1) * IN_DIM + i];
        const float r2 = x[(size_t)(row0 + 2) * IN_DIM + i];
        const float r3 = x[(size_t)(row0 + 3) * IN_DIM + i];
        buf[i] = make_uint2(f2h(r0, r1), f2h(r2, r3));
    }

    // prologue: layer-0 chunk-0 idx + coef in flight while rows stage
    unsigned pk[CHUNK];
    uint2    cc[CHUNK];
#pragma unroll
    for (int j = 0; j < CHUNK; ++j) {
        pk[j] = sidx[tid + j * THREADS];
        cc[j] = hcf[tid + j * THREADS];
    }

    __syncthreads();

    float a0 = 0.f, a1 = 0.f, a2 = 0.f, a3 = 0.f;

#pragma unroll
    for (int l = 0; l < NLAYER; ++l) {
        const uint2*    __restrict__ cl = hcf  + (size_t)l * G_DIM;
        const unsigned* __restrict__ sl = sidx + (size_t)l * G_DIM;
        uint2 o[GPT];                        // dead (DCE'd) for the last layer

#pragma unroll
        for (int ch = 0; ch < NCHUNK; ++ch) {
            // issue NEXT chunk's idx+coef (next layer's chunk 0 at layer tail)
            unsigned pkn[CHUNK];
            uint2    ccn[CHUNK];
            if (ch + 1 < NCHUNK) {
#pragma unroll
                for (int j = 0; j < CHUNK; ++j) {
                    pkn[j] = sl[tid + ((ch + 1) * CHUNK + j) * THREADS];
                    ccn[j] = cl[tid + ((ch + 1) * CHUNK + j) * THREADS];
                }
            } else if (l + 1 < NLAYER) {
                const unsigned* __restrict__ sn = sidx + (size_t)(l + 1) * G_DIM;
                const uint2*    __restrict__ cn = hcf  + (size_t)(l + 1) * G_DIM;
#pragma unroll
                for (int j = 0; j < CHUNK; ++j) {
                    pkn[j] = sn[tid + j * THREADS];
                    ccn[j] = cn[tid + j * THREADS];
                }
            }

            float lw[CHUNK];
            if (l == NLAYER - 1) {
#pragma unroll
                for (int j = 0; j < CHUNK; ++j)
                    lw[j] = lin_w[tid + (ch * CHUNK + j) * THREADS];
            }

            // gather + fma (idx+coef already resident)
#pragma unroll
            for (int j = 0; j < CHUNK; ++j) {
                const uint2 Au = buf[pk[j] & 0xFFFFu];
                const uint2 Bu = buf[pk[j] >> 16];
                const float2 A01 = h2f(Au.x), A23 = h2f(Au.y);
                const float2 B01 = h2f(Bu.x), B23 = h2f(Bu.y);
                const float2 c01 = h2f(cc[j].x);   // {c0, c1}
                const float2 c23 = h2f(cc[j].y);   // {c2, c3}
                const float o0 = fmaf(fmaf(c23.y, B01.x, c01.y), A01.x, fmaf(c23.x, B01.x, c01.x));
                const float o1 = fmaf(fmaf(c23.y, B01.y, c01.y), A01.y, fmaf(c23.x, B01.y, c01.x));
                const float o2 = fmaf(fmaf(c23.y, B23.x, c01.y), A23.x, fmaf(c23.x, B23.x, c01.x));
                const float o3 = fmaf(fmaf(c23.y, B23.y, c01.y), A23.y, fmaf(c23.x, B23.y, c01.x));
                if (l < NLAYER - 1) {
                    o[ch * CHUNK + j] = make_uint2(f2h(o0, o1), f2h(o2, o3));
                } else {
                    a0 = fmaf(o0, lw[j], a0);
                    a1 = fmaf(o1, lw[j], a1);
                    a2 = fmaf(o2, lw[j], a2);
                    a3 = fmaf(o3, lw[j], a3);
                }
            }

            // rotate pipeline registers
            if (ch + 1 < NCHUNK || l + 1 < NLAYER) {
#pragma unroll
                for (int j = 0; j < CHUNK; ++j) { pk[j] = pkn[j]; cc[j] = ccn[j]; }
            }
        }

        if (l < NLAYER - 1) {
            __syncthreads();   // all reads of this layer done
#pragma unroll
            for (int i = 0; i < GPT; ++i) buf[tid + i * THREADS] = o[i];
            __syncthreads();   // layer fully materialized
        }
    }

    // cross-lane / cross-wave reduction (4 rows)
#pragma unroll
    for (int off = 32; off > 0; off >>= 1) {
        a0 += __shfl_down(a0, off);
        a1 += __shfl_down(a1, off);
        a2 += __shfl_down(a2, off);
        a3 += __shfl_down(a3, off);
    }
    const int lane = tid & 63, wid = tid >> 6;
    if (lane == 0) { red[0][wid] = a0; red[1][wid] = a1; red[2][wid] = a2; red[3][wid] = a3; }
    __syncthreads();
    if (tid < ROWS) {
        float s = 0.f;
#pragma unroll
        for (int k = 0; k < THREADS / 64; ++k) s += red[tid][k];
        out[row0 + tid] = s + lin_b[0];
    }
}

// ---- fallback (small ws): exact f32, inline softmax (correctness only) ----
__global__ __launch_bounds__(THREADS, 1) void fused_fallback_kernel(
    const float* __restrict__ x, Ptrs P,
    const float* __restrict__ lin_w, const float* __restrict__ lin_b,
    float* __restrict__ out)
{
    __shared__ float2 buf[G_DIM];
    __shared__ float red0[THREADS / 64];
    __shared__ float red1[THREADS / 64];
    const int tid  = threadIdx.x;
    const int row0 = blockIdx.x * 2;
    for (int i = tid; i < IN_DIM; i += THREADS)
        buf[i] = make_float2(x[(size_t)row0 * IN_DIM + i],
                             x[(size_t)(row0 + 1) * IN_DIM + i]);
    __syncthreads();
    float2 o[GPT];
    for (int l = 0; l < NLAYER; ++l) {
        const int2* __restrict__ idxl = (const int2*)P.idx[l];
#pragma unroll
        for (int i = 0; i < GPT; ++i) {
            const int g = tid + i * THREADS;
            const int2 p = idxl[g];
            const float4 c = softmax_coef(P.w[l], g);
            const float2 Ap = buf[p.x];
            const float2 Bp = buf[p.y];
            o[i].x = fmaf(fmaf(c.w, Bp.x, c.y), Ap.x, fmaf(c.z, Bp.x, c.x));
            o[i].y = fmaf(fmaf(c.w, Bp.y, c.y), Ap.y, fmaf(c.z, Bp.y, c.x));
        }
        __syncthreads();
#pragma unroll
        for (int i = 0; i < GPT; ++i) buf[tid + i * THREADS] = o[i];
        __syncthreads();
    }
    float a0 = 0.f, a1 = 0.f;
#pragma unroll
    for (int i = 0; i < GPT; ++i) {
        const int g = tid + i * THREADS;
        const float lw = lin_w[g];
        const float2 bv = buf[g];
        a0 = fmaf(bv.x, lw, a0);
        a1 = fmaf(bv.y, lw, a1);
    }
#pragma unroll
    for (int off = 32; off > 0; off >>= 1) {
        a0 += __shfl_down(a0, off);
        a1 += __shfl_down(a1, off);
    }
    const int lane = tid & 63, wid = tid >> 6;
    if (lane == 0) { red0[wid] = a0; red1[wid] = a1; }
    __syncthreads();
    if (tid == 0) {
        float s0 = 0.f, s1 = 0.f;
#pragma unroll
        for (int k = 0; k < THREADS / 64; ++k) { s0 += red0[k]; s1 += red1[k]; }
        const float lb = lin_b[0];
        out[row0]     = s0 + lb;
        out[row0 + 1] = s1 + lb;
    }
}

extern "C" void kernel_launch(void* const* d_in, const int* in_sizes, int n_in,
                              void* d_out, int out_size, void* d_ws, size_t ws_size,
                              hipStream_t stream) {
    // layout: [x, idx0, w0, idx1, w1, ..., idx5, w5, lin_w, lin_b]
    const float* x = (const float*)d_in[0];
    Ptrs P;
    for (int l = 0; l < NLAYER; ++l) {
        P.idx[l] = (const int*)d_in[1 + 2 * l];
        P.w[l]   = (const float*)d_in[2 + 2 * l];
    }
    const float* lin_w = (const float*)d_in[13];
    const float* lin_b = (const float*)d_in[14];
    float* out = (float*)d_out;

    const size_t hcf_bytes  = (size_t)NLAYER * G_DIM * sizeof(uint2);
    const size_t sidx_bytes = (size_t)NLAYER * G_DIM * sizeof(unsigned);
    if (ws_size >= hcf_bytes + sidx_bytes) {
        uint2*    hcf  = (uint2*)d_ws;
        unsigned* sidx = (unsigned*)((char*)d_ws + hcf_bytes);
        dim3 cgrid(G_DIM / 256, NLAYER);
        pack_kernel<<<cgrid, 256, 0, stream>>>(P, hcf, sidx);
        fused_ws_kernel<<<N_BATCH / ROWS, THREADS, 0, stream>>>(
            x, hcf, sidx, lin_w, lin_b, out);
    } else {
        fused_fallback_kernel<<<N_BATCH / 2, THREADS, 0, stream>>>(
            x, P, lin_w, lin_b, out);
    }
}

// Round 11
// 57.988 us; speedup vs baseline: 4.1865x; 1.0086x over previous
//
#include <hip/hip_runtime.h>
#include <hip/hip_fp16.h>

#define G_DIM 16384
#define N_BATCH 2048
#define IN_DIM 1024
#define NLAYER 6
#define THREADS 1024
#define GPT 16                 // gates per thread
#define CHUNK 4
#define NCHUNK (GPT / CHUNK)
#define ROWS 4                 // batch rows per block

typedef float f32x2 __attribute__((ext_vector_type(2)));

struct Ptrs {
    const int*   idx[NLAYER];
    const float* w[NLAYER];
};

__device__ __forceinline__ float2 h2f(unsigned u) {
    __half2 h; *reinterpret_cast<unsigned*>(&h) = u;
    return __half22float2(h);
}
__device__ __forceinline__ unsigned f2h(float a, float b) {
    __half2 h = __floats2half2_rn(a, b);
    return *reinterpret_cast<unsigned*>(&h);
}

// ---- v_pk_fma_f32 helpers (exact f32 IEEE fma per component) ----
// plain: d = a*b + c (componentwise)
__device__ __forceinline__ f32x2 pk_fma(f32x2 a, f32x2 b, f32x2 c) {
    f32x2 d;
    asm("v_pk_fma_f32 %0, %1, %2, %3" : "=v"(d) : "v"(a), "v"(b), "v"(c));
    return d;
}
// d = a.y * b + c.y   (broadcast hi of src0 and src2)
__device__ __forceinline__ f32x2 pk_fma_hxh(f32x2 a, f32x2 b, f32x2 c) {
    f32x2 d;
    asm("v_pk_fma_f32 %0, %1, %2, %3 op_sel:[1,0,1] op_sel_hi:[1,1,1]"
        : "=v"(d) : "v"(a), "v"(b), "v"(c));
    return d;
}
// d = a.x * b + c.x   (broadcast lo of src0 and src2)
__device__ __forceinline__ f32x2 pk_fma_lxl(f32x2 a, f32x2 b, f32x2 c) {
    f32x2 d;
    asm("v_pk_fma_f32 %0, %1, %2, %3 op_sel:[0,0,0] op_sel_hi:[0,1,0]"
        : "=v"(d) : "v"(a), "v"(b), "v"(c));
    return d;
}
// d = a * b.x + c     (broadcast lo of src1)
__device__ __forceinline__ f32x2 pk_fma_s1l(f32x2 a, f32x2 b, f32x2 c) {
    f32x2 d;
    asm("v_pk_fma_f32 %0, %1, %2, %3 op_sel:[0,0,0] op_sel_hi:[1,0,1]"
        : "=v"(d) : "v"(a), "v"(b), "v"(c));
    return d;
}

__device__ __forceinline__ float4 softmax_coef(const float* __restrict__ w, int g) {
    float v[16];
    float m = -1e30f;
#pragma unroll
    for (int k = 0; k < 16; ++k) { v[k] = w[k * G_DIM + g]; m = fmaxf(m, v[k]); }
    float s = 0.f;
#pragma unroll
    for (int k = 0; k < 16; ++k) { v[k] = expf(v[k] - m); s += v[k]; }
    const float inv = 1.f / s;
    float4 c;
    c.x = (v[8]+v[9]+v[10]+v[11]+v[12]+v[13]+v[14]+v[15]) * inv;
    c.y = (v[2]+v[3]+v[6]+v[7] - v[8]-v[9]-v[12]-v[13]) * inv;
    c.z = (v[4]+v[5]+v[6]+v[7] - v[8]-v[9]-v[10]-v[11]) * inv;
    c.w = (v[1]-v[2]-v[4]-2.f*v[6]-v[7]+v[8]+2.f*v[9]+v[11]+v[13]-v[14]) * inv;
    return c;
}

// ---- precompute: coef[l][g] as half4 (uint2) and packed idx (lo16=A, hi16=B) ----
__global__ __launch_bounds__(256) void pack_kernel(Ptrs P, uint2* __restrict__ hcf,
                                                   unsigned* __restrict__ sidx) {
    const int g = blockIdx.x * blockDim.x + threadIdx.x;
    const int l = blockIdx.y;
    const float4 c = softmax_coef(P.w[l], g);
    hcf[(size_t)l * G_DIM + g] = make_uint2(f2h(c.x, c.y), f2h(c.z, c.w));
    const int2 p = ((const int2*)P.idx[l])[g];
    sidx[(size_t)l * G_DIM + g] = (unsigned)p.x | ((unsigned)p.y << 16);
}

// ---- main fused kernel: 4 batch rows per block as uint2{half2,half2} in LDS.
//      idx+coef software-pipelined one chunk ahead; gate math via
//      v_pk_fma_f32 with op_sel coefficient broadcasts (2 rows/instr). ----
__global__ __launch_bounds__(THREADS) void fused_ws_kernel(
    const float* __restrict__ x,
    const uint2* __restrict__ hcf,
    const unsigned* __restrict__ sidx,
    const float* __restrict__ lin_w,
    const float* __restrict__ lin_b,
    float* __restrict__ out)
{
    __shared__ uint2 buf[G_DIM];             // 128 KB: {h2(r0,r1), h2(r2,r3)}
    __shared__ float red[ROWS][THREADS / 64];

    const int tid  = threadIdx.x;
    const int row0 = blockIdx.x * ROWS;

#pragma unroll
    for (int i = tid; i < IN_DIM; i += THREADS) {
        const float r0 = x[(size_t)(row0 + 0) * IN_DIM + i];
        const float r1 = x[(size_t)(row0 + 1) * IN_DIM + i];
        const float r2 = x[(size_t)(row0 + 2) * IN_DIM + i];
        const float r3 = x[(size_t)(row0 + 3) * IN_DIM + i];
        buf[i] = make_uint2(f2h(r0, r1), f2h(r2, r3));
    }

    // prologue: layer-0 chunk-0 idx + coef in flight while rows stage
    unsigned pk[CHUNK];
    uint2    cc[CHUNK];
#pragma unroll
    for (int j = 0; j < CHUNK; ++j) {
        pk[j] = sidx[tid + j * THREADS];
        cc[j] = hcf[tid + j * THREADS];
    }

    __syncthreads();

    f32x2 acc01 = {0.f, 0.f}, acc23 = {0.f, 0.f};

#pragma unroll
    for (int l = 0; l < NLAYER; ++l) {
        const uint2*    __restrict__ cl = hcf  + (size_t)l * G_DIM;
        const unsigned* __restrict__ sl = sidx + (size_t)l * G_DIM;
        uint2 o[GPT];                        // dead (DCE'd) for the last layer

#pragma unroll
        for (int ch = 0; ch < NCHUNK; ++ch) {
            // issue NEXT chunk's idx+coef (next layer's chunk 0 at layer tail)
            unsigned pkn[CHUNK];
            uint2    ccn[CHUNK];
            if (ch + 1 < NCHUNK) {
#pragma unroll
                for (int j = 0; j < CHUNK; ++j) {
                    pkn[j] = sl[tid + ((ch + 1) * CHUNK + j) * THREADS];
                    ccn[j] = cl[tid + ((ch + 1) * CHUNK + j) * THREADS];
                }
            } else if (l + 1 < NLAYER) {
                const unsigned* __restrict__ sn = sidx + (size_t)(l + 1) * G_DIM;
                const uint2*    __restrict__ cn = hcf  + (size_t)(l + 1) * G_DIM;
#pragma unroll
                for (int j = 0; j < CHUNK; ++j) {
                    pkn[j] = sn[tid + j * THREADS];
                    ccn[j] = cn[tid + j * THREADS];
                }
            }

            float lw[CHUNK];
            if (l == NLAYER - 1) {
#pragma unroll
                for (int j = 0; j < CHUNK; ++j)
                    lw[j] = lin_w[tid + (ch * CHUNK + j) * THREADS];
            }

            // gather + packed fma (idx+coef already resident)
#pragma unroll
            for (int j = 0; j < CHUNK; ++j) {
                const uint2 Au = buf[pk[j] & 0xFFFFu];
                const uint2 Bu = buf[pk[j] >> 16];
                const float2 A01f = h2f(Au.x), A23f = h2f(Au.y);
                const float2 B01f = h2f(Bu.x), B23f = h2f(Bu.y);
                const float2 c01f = h2f(cc[j].x);   // {c0, c1}
                const float2 c23f = h2f(cc[j].y);   // {c2, c3}
                const f32x2 A01 = {A01f.x, A01f.y}, A23 = {A23f.x, A23f.y};
                const f32x2 B01 = {B01f.x, B01f.y}, B23 = {B23f.x, B23f.y};
                const f32x2 c01 = {c01f.x, c01f.y}, c23 = {c23f.x, c23f.y};
                // u = c3*B + c1 ; v = c2*B + c0 ; o = u*A + v  (per 2-row pair)
                const f32x2 u01 = pk_fma_hxh(c23, B01, c01);
                const f32x2 v01 = pk_fma_lxl(c23, B01, c01);
                const f32x2 o01 = pk_fma(u01, A01, v01);
                const f32x2 u23 = pk_fma_hxh(c23, B23, c01);
                const f32x2 v23 = pk_fma_lxl(c23, B23, c01);
                const f32x2 o23 = pk_fma(u23, A23, v23);
                if (l < NLAYER - 1) {
                    o[ch * CHUNK + j] = make_uint2(f2h(o01.x, o01.y), f2h(o23.x, o23.y));
                } else {
                    const f32x2 lwp = {lw[j], lw[j]};
                    acc01 = pk_fma_s1l(o01, lwp, acc01);
                    acc23 = pk_fma_s1l(o23, lwp, acc23);
                }
            }

            // rotate pipeline registers
            if (ch + 1 < NCHUNK || l + 1 < NLAYER) {
#pragma unroll
                for (int j = 0; j < CHUNK; ++j) { pk[j] = pkn[j]; cc[j] = ccn[j]; }
            }
        }

        if (l < NLAYER - 1) {
            __syncthreads();   // all reads of this layer done
#pragma unroll
            for (int i = 0; i < GPT; ++i) buf[tid + i * THREADS] = o[i];
            __syncthreads();   // layer fully materialized
        }
    }

    // cross-lane / cross-wave reduction (4 rows)
    float a0 = acc01.x, a1 = acc01.y, a2 = acc23.x, a3 = acc23.y;
#pragma unroll
    for (int off = 32; off > 0; off >>= 1) {
        a0 += __shfl_down(a0, off);
        a1 += __shfl_down(a1, off);
        a2 += __shfl_down(a2, off);
        a3 += __shfl_down(a3, off);
    }
    const int lane = tid & 63, wid = tid >> 6;
    if (lane == 0) { red[0][wid] = a0; red[1][wid] = a1; red[2][wid] = a2; red[3][wid] = a3; }
    __syncthreads();
    if (tid < ROWS) {
        float s = 0.f;
#pragma unroll
        for (int k = 0; k < THREADS / 64; ++k) s += red[tid][k];
        out[row0 + tid] = s + lin_b[0];
    }
}

// ---- fallback (small ws): exact f32, inline softmax (correctness only) ----
__global__ __launch_bounds__(THREADS, 1) void fused_fallback_kernel(
    const float* __restrict__ x, Ptrs P,
    const float* __restrict__ lin_w, const float* __restrict__ lin_b,
    float* __restrict__ out)
{
    __shared__ float2 buf[G_DIM];
    __shared__ float red0[THREADS / 64];
    __shared__ float red1[THREADS / 64];
    const int tid  = threadIdx.x;
    const int row0 = blockIdx.x * 2;
    for (int i = tid; i < IN_DIM; i += THREADS)
        buf[i] = make_float2(x[(size_t)row0 * IN_DIM + i],
                             x[(size_t)(row0 + 1) * IN_DIM + i]);
    __syncthreads();
    float2 o[GPT];
    for (int l = 0; l < NLAYER; ++l) {
        const int2* __restrict__ idxl = (const int2*)P.idx[l];
#pragma unroll
        for (int i = 0; i < GPT; ++i) {
            const int g = tid + i * THREADS;
            const int2 p = idxl[g];
            const float4 c = softmax_coef(P.w[l], g);
            const float2 Ap = buf[p.x];
            const float2 Bp = buf[p.y];
            o[i].x = fmaf(fmaf(c.w, Bp.x, c.y), Ap.x, fmaf(c.z, Bp.x, c.x));
            o[i].y = fmaf(fmaf(c.w, Bp.y, c.y), Ap.y, fmaf(c.z, Bp.y, c.x));
        }
        __syncthreads();
#pragma unroll
        for (int i = 0; i < GPT; ++i) buf[tid + i * THREADS] = o[i];
        __syncthreads();
    }
    float a0 = 0.f, a1 = 0.f;
#pragma unroll
    for (int i = 0; i < GPT; ++i) {
        const int g = tid + i * THREADS;
        const float lw = lin_w[g];
        const float2 bv = buf[g];
        a0 = fmaf(bv.x, lw, a0);
        a1 = fmaf(bv.y, lw, a1);
    }
#pragma unroll
    for (int off = 32; off > 0; off >>= 1) {
        a0 += __shfl_down(a0, off);
        a1 += __shfl_down(a1, off);
    }
    const int lane = tid & 63, wid = tid >> 6;
    if (lane == 0) { red0[wid] = a0; red1[wid] = a1; }
    __syncthreads();
    if (tid == 0) {
        float s0 = 0.f, s1 = 0.f;
#pragma unroll
        for (int k = 0; k < THREADS / 64; ++k) { s0 += red0[k]; s1 += red1[k]; }
        const float lb = lin_b[0];
        out[row0]     = s0 + lb;
        out[row0 + 1] = s1 + lb;
    }
}

extern "C" void kernel_launch(void* const* d_in, const int* in_sizes, int n_in,
                              void* d_out, int out_size, void* d_ws, size_t ws_size,
                              hipStream_t stream) {
    // layout: [x, idx0, w0, idx1, w1, ..., idx5, w5, lin_w, lin_b]
    const float* x = (const float*)d_in[0];
    Ptrs P;
    for (int l = 0; l < NLAYER; ++l) {
        P.idx[l] = (const int*)d_in[1 + 2 * l];
        P.w[l]   = (const float*)d_in[2 + 2 * l];
    }
    const float* lin_w = (const float*)d_in[13];
    const float* lin_b = (const float*)d_in[14];
    float* out = (float*)d_out;

    const size_t hcf_bytes  = (size_t)NLAYER * G_DIM * sizeof(uint2);
    const size_t sidx_bytes = (size_t)NLAYER * G_DIM * sizeof(unsigned);
    if (ws_size >= hcf_bytes + sidx_bytes) {
        uint2*    hcf  = (uint2*)d_ws;
        unsigned* sidx = (unsigned*)((char*)d_ws + hcf_bytes);
        dim3 cgrid(G_DIM / 256, NLAYER);
        pack_kernel<<<cgrid, 256, 0, stream>>>(P, hcf, sidx);
        fused_ws_kernel<<<N_BATCH / ROWS, THREADS, 0, stream>>>(
            x, hcf, sidx, lin_w, lin_b, out);
    } else {
        fused_fallback_kernel<<<N_BATCH / 2, THREADS, 0, stream>>>(
            x, P, lin_w, lin_b, out);
    }
}

// Round 12
// 56.363 us; speedup vs baseline: 4.3072x; 1.0288x over previous
//
#include <hip/hip_runtime.h>
#include <hip/hip_fp16.h>

#define G_DIM 16384
#define N_BATCH 2048
#define IN_DIM 1024
#define NLAYER 6
#define THREADS 1024
#define GPT 16                 // gates per thread
#define CHUNK 4
#define NCHUNK (GPT / CHUNK)
#define ROWS 4                 // batch rows per block

struct Ptrs {
    const int*   idx[NLAYER];
    const float* w[NLAYER];
};

__device__ __forceinline__ unsigned f2h(float a, float b) {
    __half2 h = __floats2half2_rn(a, b);
    return *reinterpret_cast<unsigned*>(&h);
}

// ---- v_fma_mix helpers: f32 = f16/f32 operands, fma in f32 ----
// d = hi(a)*lo(b) + hi(c)   (all f16 inputs)
__device__ __forceinline__ float mix_hlh(unsigned a, unsigned b, unsigned c) {
    float d;
    asm("v_fma_mix_f32 %0, %1, %2, %3 op_sel:[1,0,1] op_sel_hi:[1,1,1]"
        : "=v"(d) : "v"(a), "v"(b), "v"(c));
    return d;
}
// d = hi(a)*hi(b) + hi(c)
__device__ __forceinline__ float mix_hhh(unsigned a, unsigned b, unsigned c) {
    float d;
    asm("v_fma_mix_f32 %0, %1, %2, %3 op_sel:[1,1,1] op_sel_hi:[1,1,1]"
        : "=v"(d) : "v"(a), "v"(b), "v"(c));
    return d;
}
// d = lo(a)*lo(b) + lo(c)
__device__ __forceinline__ float mix_lll(unsigned a, unsigned b, unsigned c) {
    float d;
    asm("v_fma_mix_f32 %0, %1, %2, %3 op_sel:[0,0,0] op_sel_hi:[1,1,1]"
        : "=v"(d) : "v"(a), "v"(b), "v"(c));
    return d;
}
// d = lo(a)*hi(b) + lo(c)
__device__ __forceinline__ float mix_lhl(unsigned a, unsigned b, unsigned c) {
    float d;
    asm("v_fma_mix_f32 %0, %1, %2, %3 op_sel:[0,1,0] op_sel_hi:[1,1,1]"
        : "=v"(d) : "v"(a), "v"(b), "v"(c));
    return d;
}
// d(f32) = u(f32) * lo(A)(f16) + v(f32)
__device__ __forceinline__ float mix_alo(float u, unsigned A, float v) {
    float d;
    asm("v_fma_mix_f32 %0, %1, %2, %3 op_sel:[0,0,0] op_sel_hi:[0,1,0]"
        : "=v"(d) : "v"(u), "v"(A), "v"(v));
    return d;
}
// d(f32) = u(f32) * hi(A)(f16) + v(f32)
__device__ __forceinline__ float mix_ahi(float u, unsigned A, float v) {
    float d;
    asm("v_fma_mix_f32 %0, %1, %2, %3 op_sel:[0,1,0] op_sel_hi:[0,1,0]"
        : "=v"(d) : "v"(u), "v"(A), "v"(v));
    return d;
}
// t.lo = f16rn(u * lo(A) + v); t.hi = f16rn(u2 * hi(A) + v2)
__device__ __forceinline__ unsigned mix_pack(float u0, float v0, float u1, float v1,
                                             unsigned A) {
    unsigned t;
    asm("v_fma_mixlo_f16 %0, %1, %2, %3 op_sel:[0,0,0] op_sel_hi:[0,1,0]"
        : "=v"(t) : "v"(u0), "v"(A), "v"(v0));
    asm("v_fma_mixhi_f16 %0, %1, %2, %3 op_sel:[0,1,0] op_sel_hi:[0,1,0]"
        : "+v"(t) : "v"(u1), "v"(A), "v"(v1));
    return t;
}

__device__ __forceinline__ float4 softmax_coef(const float* __restrict__ w, int g) {
    float v[16];
    float m = -1e30f;
#pragma unroll
    for (int k = 0; k < 16; ++k) { v[k] = w[k * G_DIM + g]; m = fmaxf(m, v[k]); }
    float s = 0.f;
#pragma unroll
    for (int k = 0; k < 16; ++k) { v[k] = expf(v[k] - m); s += v[k]; }
    const float inv = 1.f / s;
    float4 c;
    c.x = (v[8]+v[9]+v[10]+v[11]+v[12]+v[13]+v[14]+v[15]) * inv;
    c.y = (v[2]+v[3]+v[6]+v[7] - v[8]-v[9]-v[12]-v[13]) * inv;
    c.z = (v[4]+v[5]+v[6]+v[7] - v[8]-v[9]-v[10]-v[11]) * inv;
    c.w = (v[1]-v[2]-v[4]-2.f*v[6]-v[7]+v[8]+2.f*v[9]+v[11]+v[13]-v[14]) * inv;
    return c;
}

// ---- precompute: coef[l][g] as half4 (uint2) and packed idx (lo16=A, hi16=B) ----
__global__ __launch_bounds__(256) void pack_kernel(Ptrs P, uint2* __restrict__ hcf,
                                                   unsigned* __restrict__ sidx) {
    const int g = blockIdx.x * blockDim.x + threadIdx.x;
    const int l = blockIdx.y;
    const float4 c = softmax_coef(P.w[l], g);
    hcf[(size_t)l * G_DIM + g] = make_uint2(f2h(c.x, c.y), f2h(c.z, c.w));
    const int2 p = ((const int2*)P.idx[l])[g];
    sidx[(size_t)l * G_DIM + g] = (unsigned)p.x | ((unsigned)p.y << 16);
}

// ---- main fused kernel: 4 batch rows per block as uint2{half2,half2} in LDS.
//      idx+coef software-pipelined one chunk ahead; gate math entirely in
//      v_fma_mix (f16 operands consumed packed, f32 fma, f16-RN packed store:
//      zero cvt/pack instructions; bit-identical to the f32-compute path). ----
__global__ __launch_bounds__(THREADS) void fused_ws_kernel(
    const float* __restrict__ x,
    const uint2* __restrict__ hcf,
    const unsigned* __restrict__ sidx,
    const float* __restrict__ lin_w,
    const float* __restrict__ lin_b,
    float* __restrict__ out)
{
    __shared__ uint2 buf[G_DIM];             // 128 KB: {h2(r0,r1), h2(r2,r3)}
    __shared__ float red[ROWS][THREADS / 64];

    const int tid  = threadIdx.x;
    const int row0 = blockIdx.x * ROWS;

#pragma unroll
    for (int i = tid; i < IN_DIM; i += THREADS) {
        const float r0 = x[(size_t)(row0 + 0) * IN_DIM + i];
        const float r1 = x[(size_t)(row0 + 1) * IN_DIM + i];
        const float r2 = x[(size_t)(row0 + 2) * IN_DIM + i];
        const float r3 = x[(size_t)(row0 + 3) * IN_DIM + i];
        buf[i] = make_uint2(f2h(r0, r1), f2h(r2, r3));
    }

    // prologue: layer-0 chunk-0 idx + coef in flight while rows stage
    unsigned pk[CHUNK];
    uint2    cc[CHUNK];
#pragma unroll
    for (int j = 0; j < CHUNK; ++j) {
        pk[j] = sidx[tid + j * THREADS];
        cc[j] = hcf[tid + j * THREADS];
    }

    __syncthreads();

    float a0 = 0.f, a1 = 0.f, a2 = 0.f, a3 = 0.f;

#pragma unroll
    for (int l = 0; l < NLAYER; ++l) {
        const uint2*    __restrict__ cl = hcf  + (size_t)l * G_DIM;
        const unsigned* __restrict__ sl = sidx + (size_t)l * G_DIM;
        uint2 o[GPT];                        // dead (DCE'd) for the last layer

#pragma unroll
        for (int ch = 0; ch < NCHUNK; ++ch) {
            // issue NEXT chunk's idx+coef (next layer's chunk 0 at layer tail)
            unsigned pkn[CHUNK];
            uint2    ccn[CHUNK];
            if (ch + 1 < NCHUNK) {
#pragma unroll
                for (int j = 0; j < CHUNK; ++j) {
                    pkn[j] = sl[tid + ((ch + 1) * CHUNK + j) * THREADS];
                    ccn[j] = cl[tid + ((ch + 1) * CHUNK + j) * THREADS];
                }
            } else if (l + 1 < NLAYER) {
                const unsigned* __restrict__ sn = sidx + (size_t)(l + 1) * G_DIM;
                const uint2*    __restrict__ cn = hcf  + (size_t)(l + 1) * G_DIM;
#pragma unroll
                for (int j = 0; j < CHUNK; ++j) {
                    pkn[j] = sn[tid + j * THREADS];
                    ccn[j] = cn[tid + j * THREADS];
                }
            }

            float lw[CHUNK];
            if (l == NLAYER - 1) {
#pragma unroll
                for (int j = 0; j < CHUNK; ++j)
                    lw[j] = lin_w[tid + (ch * CHUNK + j) * THREADS];
            }

            // gather + mixed-precision fma (idx+coef already resident)
#pragma unroll
            for (int j = 0; j < CHUNK; ++j) {
                const uint2 Au = buf[pk[j] & 0xFFFFu];
                const uint2 Bu = buf[pk[j] >> 16];
                const unsigned c01 = cc[j].x;       // {c0, c1} packed f16
                const unsigned c23 = cc[j].y;       // {c2, c3} packed f16
                // u_r = c3*B_r + c1 ; v_r = c2*B_r + c0   (f32 results)
                const float u0 = mix_hlh(c23, Bu.x, c01);
                const float u1 = mix_hhh(c23, Bu.x, c01);
                const float v0 = mix_lll(c23, Bu.x, c01);
                const float v1 = mix_lhl(c23, Bu.x, c01);
                const float u2 = mix_hlh(c23, Bu.y, c01);
                const float u3 = mix_hhh(c23, Bu.y, c01);
                const float v2 = mix_lll(c23, Bu.y, c01);
                const float v3 = mix_lhl(c23, Bu.y, c01);
                if (l < NLAYER - 1) {
                    // o_r = f16rn(u_r * A_r + v_r), packed directly
                    const unsigned t01 = mix_pack(u0, v0, u1, v1, Au.x);
                    const unsigned t23 = mix_pack(u2, v2, u3, v3, Au.y);
                    o[ch * CHUNK + j] = make_uint2(t01, t23);
                } else {
                    const float o0 = mix_alo(u0, Au.x, v0);
                    const float o1 = mix_ahi(u1, Au.x, v1);
                    const float o2 = mix_alo(u2, Au.y, v2);
                    const float o3 = mix_ahi(u3, Au.y, v3);
                    a0 = fmaf(o0, lw[j], a0);
                    a1 = fmaf(o1, lw[j], a1);
                    a2 = fmaf(o2, lw[j], a2);
                    a3 = fmaf(o3, lw[j], a3);
                }
            }

            // rotate pipeline registers
            if (ch + 1 < NCHUNK || l + 1 < NLAYER) {
#pragma unroll
                for (int j = 0; j < CHUNK; ++j) { pk[j] = pkn[j]; cc[j] = ccn[j]; }
            }
        }

        if (l < NLAYER - 1) {
            __syncthreads();   // all reads of this layer done
#pragma unroll
            for (int i = 0; i < GPT; ++i) buf[tid + i * THREADS] = o[i];
            __syncthreads();   // layer fully materialized
        }
    }

    // cross-lane / cross-wave reduction (4 rows)
#pragma unroll
    for (int off = 32; off > 0; off >>= 1) {
        a0 += __shfl_down(a0, off);
        a1 += __shfl_down(a1, off);
        a2 += __shfl_down(a2, off);
        a3 += __shfl_down(a3, off);
    }
    const int lane = tid & 63, wid = tid >> 6;
    if (lane == 0) { red[0][wid] = a0; red[1][wid] = a1; red[2][wid] = a2; red[3][wid] = a3; }
    __syncthreads();
    if (tid < ROWS) {
        float s = 0.f;
#pragma unroll
        for (int k = 0; k < THREADS / 64; ++k) s += red[tid][k];
        out[row0 + tid] = s + lin_b[0];
    }
}

// ---- fallback (small ws): exact f32, inline softmax (correctness only) ----
__global__ __launch_bounds__(THREADS, 1) void fused_fallback_kernel(
    const float* __restrict__ x, Ptrs P,
    const float* __restrict__ lin_w, const float* __restrict__ lin_b,
    float* __restrict__ out)
{
    __shared__ float2 buf[G_DIM];
    __shared__ float red0[THREADS / 64];
    __shared__ float red1[THREADS / 64];
    const int tid  = threadIdx.x;
    const int row0 = blockIdx.x * 2;
    for (int i = tid; i < IN_DIM; i += THREADS)
        buf[i] = make_float2(x[(size_t)row0 * IN_DIM + i],
                             x[(size_t)(row0 + 1) * IN_DIM + i]);
    __syncthreads();
    float2 o[GPT];
    for (int l = 0; l < NLAYER; ++l) {
        const int2* __restrict__ idxl = (const int2*)P.idx[l];
#pragma unroll
        for (int i = 0; i < GPT; ++i) {
            const int g = tid + i * THREADS;
            const int2 p = idxl[g];
            const float4 c = softmax_coef(P.w[l], g);
            const float2 Ap = buf[p.x];
            const float2 Bp = buf[p.y];
            o[i].x = fmaf(fmaf(c.w, Bp.x, c.y), Ap.x, fmaf(c.z, Bp.x, c.x));
            o[i].y = fmaf(fmaf(c.w, Bp.y, c.y), Ap.y, fmaf(c.z, Bp.y, c.x));
        }
        __syncthreads();
#pragma unroll
        for (int i = 0; i < GPT; ++i) buf[tid + i * THREADS] = o[i];
        __syncthreads();
    }
    float a0 = 0.f, a1 = 0.f;
#pragma unroll
    for (int i = 0; i < GPT; ++i) {
        const int g = tid + i * THREADS;
        const float lw = lin_w[g];
        const float2 bv = buf[g];
        a0 = fmaf(bv.x, lw, a0);
        a1 = fmaf(bv.y, lw, a1);
    }
#pragma unroll
    for (int off = 32; off > 0; off >>= 1) {
        a0 += __shfl_down(a0, off);
        a1 += __shfl_down(a1, off);
    }
    const int lane = tid & 63, wid = tid >> 6;
    if (lane == 0) { red0[wid] = a0; red1[wid] = a1; }
    __syncthreads();
    if (tid == 0) {
        float s0 = 0.f, s1 = 0.f;
#pragma unroll
        for (int k = 0; k < THREADS / 64; ++k) { s0 += red0[k]; s1 += red1[k]; }
        const float lb = lin_b[0];
        out[row0]     = s0 + lb;
        out[row0 + 1] = s1 + lb;
    }
}

extern "C" void kernel_launch(void* const* d_in, const int* in_sizes, int n_in,
                              void* d_out, int out_size, void* d_ws, size_t ws_size,
                              hipStream_t stream) {
    // layout: [x, idx0, w0, idx1, w1, ..., idx5, w5, lin_w, lin_b]
    const float* x = (const float*)d_in[0];
    Ptrs P;
    for (int l = 0; l < NLAYER; ++l) {
        P.idx[l] = (const int*)d_in[1 + 2 * l];
        P.w[l]   = (const float*)d_in[2 + 2 * l];
    }
    const float* lin_w = (const float*)d_in[13];
    const float* lin_b = (const float*)d_in[14];
    float* out = (float*)d_out;

    const size_t hcf_bytes  = (size_t)NLAYER * G_DIM * sizeof(uint2);
    const size_t sidx_bytes = (size_t)NLAYER * G_DIM * sizeof(unsigned);
    if (ws_size >= hcf_bytes + sidx_bytes) {
        uint2*    hcf  = (uint2*)d_ws;
        unsigned* sidx = (unsigned*)((char*)d_ws + hcf_bytes);
        dim3 cgrid(G_DIM / 256, NLAYER);
        pack_kernel<<<cgrid, 256, 0, stream>>>(P, hcf, sidx);
        fused_ws_kernel<<<N_BATCH / ROWS, THREADS, 0, stream>>>(
            x, hcf, sidx, lin_w, lin_b, out);
    } else {
        fused_fallback_kernel<<<N_BATCH / 2, THREADS, 0, stream>>>(
            x, P, lin_w, lin_b, out);
    }
}

// Round 13
// 52.907 us; speedup vs baseline: 4.5885x; 1.0653x over previous
//
#include <hip/hip_runtime.h>
#include <hip/hip_fp16.h>

#define G_DIM 16384
#define N_BATCH 2048
#define IN_DIM 1024
#define NLAYER 6
#define THREADS 1024
#define NPAIR 8                // gate-pairs per thread (16 gates)
#define NCHUNK 4               // chunks of 2 pairs
#define ROWS 4                 // batch rows per block

struct Ptrs {
    const int*   idx[NLAYER];
    const float* w[NLAYER];
};

__device__ __forceinline__ unsigned f2h(float a, float b) {
    __half2 h = __floats2half2_rn(a, b);
    return *reinterpret_cast<unsigned*>(&h);
}

// ---- v_fma_mix helpers: f16/f32 operands, fma in f32 ----
__device__ __forceinline__ float mix_hlh(unsigned a, unsigned b, unsigned c) {
    float d;
    asm("v_fma_mix_f32 %0, %1, %2, %3 op_sel:[1,0,1] op_sel_hi:[1,1,1]"
        : "=v"(d) : "v"(a), "v"(b), "v"(c));
    return d;
}
__device__ __forceinline__ float mix_hhh(unsigned a, unsigned b, unsigned c) {
    float d;
    asm("v_fma_mix_f32 %0, %1, %2, %3 op_sel:[1,1,1] op_sel_hi:[1,1,1]"
        : "=v"(d) : "v"(a), "v"(b), "v"(c));
    return d;
}
__device__ __forceinline__ float mix_lll(unsigned a, unsigned b, unsigned c) {
    float d;
    asm("v_fma_mix_f32 %0, %1, %2, %3 op_sel:[0,0,0] op_sel_hi:[1,1,1]"
        : "=v"(d) : "v"(a), "v"(b), "v"(c));
    return d;
}
__device__ __forceinline__ float mix_lhl(unsigned a, unsigned b, unsigned c) {
    float d;
    asm("v_fma_mix_f32 %0, %1, %2, %3 op_sel:[0,1,0] op_sel_hi:[1,1,1]"
        : "=v"(d) : "v"(a), "v"(b), "v"(c));
    return d;
}
__device__ __forceinline__ float mix_alo(float u, unsigned A, float v) {
    float d;
    asm("v_fma_mix_f32 %0, %1, %2, %3 op_sel:[0,0,0] op_sel_hi:[0,1,0]"
        : "=v"(d) : "v"(u), "v"(A), "v"(v));
    return d;
}
__device__ __forceinline__ float mix_ahi(float u, unsigned A, float v) {
    float d;
    asm("v_fma_mix_f32 %0, %1, %2, %3 op_sel:[0,1,0] op_sel_hi:[0,1,0]"
        : "=v"(d) : "v"(u), "v"(A), "v"(v));
    return d;
}
__device__ __forceinline__ unsigned mix_pack(float u0, float v0, float u1, float v1,
                                             unsigned A) {
    unsigned t;
    asm("v_fma_mixlo_f16 %0, %1, %2, %3 op_sel:[0,0,0] op_sel_hi:[0,1,0]"
        : "=v"(t) : "v"(u0), "v"(A), "v"(v0));
    asm("v_fma_mixhi_f16 %0, %1, %2, %3 op_sel:[0,1,0] op_sel_hi:[0,1,0]"
        : "+v"(t) : "v"(u1), "v"(A), "v"(v1));
    return t;
}

struct PairG { uint2 A0, B0, A1, B1; };   // gathered activations for a gate pair

// gathers for one pair (buf must be the LDS alias in scope)
#define GATHER(G, PK)                                     \
    do {                                                  \
        (G).A0 = buf[(PK).x & 0xFFFFu];                   \
        (G).B0 = buf[(PK).x >> 16];                       \
        (G).A1 = buf[(PK).y & 0xFFFFu];                   \
        (G).B1 = buf[(PK).y >> 16];                       \
    } while (0)

// one gate: 8 mix-fma (u,v in f32) + 2 mixlo/hi pack -> uint2{rows01, rows23}
__device__ __forceinline__ uint2 gate_fma(uint2 Au, uint2 Bu, unsigned c01, unsigned c23) {
    const float u0 = mix_hlh(c23, Bu.x, c01);
    const float u1 = mix_hhh(c23, Bu.x, c01);
    const float v0 = mix_lll(c23, Bu.x, c01);
    const float v1 = mix_lhl(c23, Bu.x, c01);
    const float u2 = mix_hlh(c23, Bu.y, c01);
    const float u3 = mix_hhh(c23, Bu.y, c01);
    const float v2 = mix_lll(c23, Bu.y, c01);
    const float v3 = mix_lhl(c23, Bu.y, c01);
    const unsigned t01 = mix_pack(u0, v0, u1, v1, Au.x);
    const unsigned t23 = mix_pack(u2, v2, u3, v3, Au.y);
    return make_uint2(t01, t23);
}
__device__ __forceinline__ void gate_acc(uint2 Au, uint2 Bu, unsigned c01, unsigned c23,
                                         float lw, float& a0, float& a1, float& a2, float& a3) {
    const float u0 = mix_hlh(c23, Bu.x, c01);
    const float u1 = mix_hhh(c23, Bu.x, c01);
    const float v0 = mix_lll(c23, Bu.x, c01);
    const float v1 = mix_lhl(c23, Bu.x, c01);
    const float u2 = mix_hlh(c23, Bu.y, c01);
    const float u3 = mix_hhh(c23, Bu.y, c01);
    const float v2 = mix_lll(c23, Bu.y, c01);
    const float v3 = mix_lhl(c23, Bu.y, c01);
    a0 = fmaf(mix_alo(u0, Au.x, v0), lw, a0);
    a1 = fmaf(mix_ahi(u1, Au.x, v1), lw, a1);
    a2 = fmaf(mix_alo(u2, Au.y, v2), lw, a2);
    a3 = fmaf(mix_ahi(u3, Au.y, v3), lw, a3);
}

__device__ __forceinline__ float4 softmax_coef(const float* __restrict__ w, int g) {
    float v[16];
    float m = -1e30f;
#pragma unroll
    for (int k = 0; k < 16; ++k) { v[k] = w[k * G_DIM + g]; m = fmaxf(m, v[k]); }
    float s = 0.f;
#pragma unroll
    for (int k = 0; k < 16; ++k) { v[k] = expf(v[k] - m); s += v[k]; }
    const float inv = 1.f / s;
    float4 c;
    c.x = (v[8]+v[9]+v[10]+v[11]+v[12]+v[13]+v[14]+v[15]) * inv;
    c.y = (v[2]+v[3]+v[6]+v[7] - v[8]-v[9]-v[12]-v[13]) * inv;
    c.z = (v[4]+v[5]+v[6]+v[7] - v[8]-v[9]-v[10]-v[11]) * inv;
    c.w = (v[1]-v[2]-v[4]-2.f*v[6]-v[7]+v[8]+2.f*v[9]+v[11]+v[13]-v[14]) * inv;
    return c;
}

// ---- precompute: coef[l][g] as half4 (uint2) and packed idx (lo16=A, hi16=B) ----
__global__ __launch_bounds__(256) void pack_kernel(Ptrs P, uint2* __restrict__ hcf,
                                                   unsigned* __restrict__ sidx) {
    const int g = blockIdx.x * blockDim.x + threadIdx.x;
    const int l = blockIdx.y;
    const float4 c = softmax_coef(P.w[l], g);
    hcf[(size_t)l * G_DIM + g] = make_uint2(f2h(c.x, c.y), f2h(c.z, c.w));
    const int2 p = ((const int2*)P.idx[l])[g];
    sidx[(size_t)l * G_DIM + g] = (unsigned)p.x | ((unsigned)p.y << 16);
}

// ---- main fused kernel: 4 rows/block as f16x4 in LDS; thread owns gate PAIRS
//      (2gp, 2gp+1): idx/coef/lin_w load as uint2/uint4/float2 (VMEM halved),
//      LDS writes b128; gathers software-pipelined one pair ahead; idx stream
//      prefetched two chunks ahead. ----
__global__ __launch_bounds__(THREADS) void fused_ws_kernel(
    const float* __restrict__ x,
    const uint2* __restrict__ hcf,
    const unsigned* __restrict__ sidx,
    const float* __restrict__ lin_w,
    const float* __restrict__ lin_b,
    float* __restrict__ out)
{
    __shared__ uint4 buf4[G_DIM / 2];        // 128 KB
    __shared__ float red[ROWS][THREADS / 64];
    uint2* buf = (uint2*)buf4;               // per-gate view {h2(r0,r1), h2(r2,r3)}

    const int tid  = threadIdx.x;
    const int row0 = blockIdx.x * ROWS;

    for (int i = tid; i < IN_DIM; i += THREADS) {
        const float r0 = x[(size_t)(row0 + 0) * IN_DIM + i];
        const float r1 = x[(size_t)(row0 + 1) * IN_DIM + i];
        const float r2 = x[(size_t)(row0 + 2) * IN_DIM + i];
        const float r3 = x[(size_t)(row0 + 3) * IN_DIM + i];
        buf[i] = make_uint2(f2h(r0, r1), f2h(r2, r3));
    }

    const uint2*  __restrict__ sidx2 = (const uint2*)sidx;   // idx per pair
    const uint4*  __restrict__ hcf4  = (const uint4*)hcf;    // coef per pair
    const float2* __restrict__ lw2   = (const float2*)lin_w; // lin_w per pair

    // prologue: layer-0 chunk0+chunk1 idx, chunk0 coef in flight while rows stage
    uint2 pkA[2], pkB[2];
    uint4 ccA[2];
#pragma unroll
    for (int j = 0; j < 2; ++j) {
        pkA[j] = sidx2[tid + j * THREADS];
        pkB[j] = sidx2[tid + (2 + j) * THREADS];
        ccA[j] = hcf4 [tid + j * THREADS];
    }

    __syncthreads();

    float a0 = 0.f, a1 = 0.f, a2 = 0.f, a3 = 0.f;

#pragma unroll
    for (int l = 0; l < NLAYER; ++l) {
        uint4 o[NPAIR];
        PairG Gc, Gn;
        GATHER(Gc, pkA[0]);                  // pair 0 of this layer

#pragma unroll
        for (int ch = 0; ch < NCHUNK; ++ch) {
            // issue idx two chunks ahead and coef one chunk ahead (may cross layer)
            uint2 pkC[2];
            uint4 ccB[2];
            const bool haveC  = (ch + 2 < NCHUNK) || (l + 1 < NLAYER);
            const bool haveB  = (ch + 1 < NCHUNK) || (l + 1 < NLAYER);
            if (haveC) {
                const int lc = (ch + 2 < NCHUNK) ? l : l + 1;
                const int cc_ = (ch + 2 < NCHUNK) ? ch + 2 : ch + 2 - NCHUNK;
                const uint2* sC = sidx2 + (size_t)lc * (G_DIM / 2);
#pragma unroll
                for (int j = 0; j < 2; ++j) pkC[j] = sC[tid + (cc_ * 2 + j) * THREADS];
            }
            if (haveB) {
                const int lb = (ch + 1 < NCHUNK) ? l : l + 1;
                const int cb = (ch + 1 < NCHUNK) ? ch + 1 : 0;
                const uint4* cB = hcf4 + (size_t)lb * (G_DIM / 2);
#pragma unroll
                for (int j = 0; j < 2; ++j) ccB[j] = cB[tid + (cb * 2 + j) * THREADS];
            }
            float2 lwp[2];
            if (l == NLAYER - 1) {
#pragma unroll
                for (int j = 0; j < 2; ++j) lwp[j] = lw2[tid + (ch * 2 + j) * THREADS];
            }

            // pair A (= ch*2): gather-ahead pair B, then fma pair A
            GATHER(Gn, pkA[1]);
            if (l < NLAYER - 1) {
                const uint2 g0 = gate_fma(Gc.A0, Gc.B0, ccA[0].x, ccA[0].y);
                const uint2 g1 = gate_fma(Gc.A1, Gc.B1, ccA[0].z, ccA[0].w);
                o[ch * 2] = make_uint4(g0.x, g0.y, g1.x, g1.y);
            } else {
                gate_acc(Gc.A0, Gc.B0, ccA[0].x, ccA[0].y, lwp[0].x, a0, a1, a2, a3);
                gate_acc(Gc.A1, Gc.B1, ccA[0].z, ccA[0].w, lwp[0].y, a0, a1, a2, a3);
            }
            // pair B (= ch*2+1): gather-ahead next chunk's pair 0 (same layer only)
            if (ch + 1 < NCHUNK) GATHER(Gc, pkB[0]);
            if (l < NLAYER - 1) {
                const uint2 g0 = gate_fma(Gn.A0, Gn.B0, ccA[1].x, ccA[1].y);
                const uint2 g1 = gate_fma(Gn.A1, Gn.B1, ccA[1].z, ccA[1].w);
                o[ch * 2 + 1] = make_uint4(g0.x, g0.y, g1.x, g1.y);
            } else {
                gate_acc(Gn.A0, Gn.B0, ccA[1].x, ccA[1].y, lwp[1].x, a0, a1, a2, a3);
                gate_acc(Gn.A1, Gn.B1, ccA[1].z, ccA[1].w, lwp[1].y, a0, a1, a2, a3);
            }

            // rotate pipeline registers
#pragma unroll
            for (int j = 0; j < 2; ++j) {
                pkA[j] = pkB[j];
                if (haveC) pkB[j] = pkC[j];
                if (haveB) ccA[j] = ccB[j];
            }
        }

        if (l < NLAYER - 1) {
            __syncthreads();   // all reads of this layer done
#pragma unroll
            for (int p = 0; p < NPAIR; ++p) buf4[tid + p * THREADS] = o[p];
            __syncthreads();   // layer fully materialized
        }
    }

    // cross-lane / cross-wave reduction (4 rows)
#pragma unroll
    for (int off = 32; off > 0; off >>= 1) {
        a0 += __shfl_down(a0, off);
        a1 += __shfl_down(a1, off);
        a2 += __shfl_down(a2, off);
        a3 += __shfl_down(a3, off);
    }
    const int lane = tid & 63, wid = tid >> 6;
    if (lane == 0) { red[0][wid] = a0; red[1][wid] = a1; red[2][wid] = a2; red[3][wid] = a3; }
    __syncthreads();
    if (tid < ROWS) {
        float s = 0.f;
#pragma unroll
        for (int k = 0; k < THREADS / 64; ++k) s += red[tid][k];
        out[row0 + tid] = s + lin_b[0];
    }
}

// ---- fallback (small ws): exact f32, inline softmax (correctness only) ----
__global__ __launch_bounds__(THREADS, 1) void fused_fallback_kernel(
    const float* __restrict__ x, Ptrs P,
    const float* __restrict__ lin_w, const float* __restrict__ lin_b,
    float* __restrict__ out)
{
    __shared__ float2 buf[G_DIM];
    __shared__ float red0[THREADS / 64];
    __shared__ float red1[THREADS / 64];
    const int tid  = threadIdx.x;
    const int row0 = blockIdx.x * 2;
    for (int i = tid; i < IN_DIM; i += THREADS)
        buf[i] = make_float2(x[(size_t)row0 * IN_DIM + i],
                             x[(size_t)(row0 + 1) * IN_DIM + i]);
    __syncthreads();
    float2 o[16];
    for (int l = 0; l < NLAYER; ++l) {
        const int2* __restrict__ idxl = (const int2*)P.idx[l];
#pragma unroll
        for (int i = 0; i < 16; ++i) {
            const int g = tid + i * THREADS;
            const int2 p = idxl[g];
            const float4 c = softmax_coef(P.w[l], g);
            const float2 Ap = buf[p.x];
            const float2 Bp = buf[p.y];
            o[i].x = fmaf(fmaf(c.w, Bp.x, c.y), Ap.x, fmaf(c.z, Bp.x, c.x));
            o[i].y = fmaf(fmaf(c.w, Bp.y, c.y), Ap.y, fmaf(c.z, Bp.y, c.x));
        }
        __syncthreads();
#pragma unroll
        for (int i = 0; i < 16; ++i) buf[tid + i * THREADS] = o[i];
        __syncthreads();
    }
    float a0 = 0.f, a1 = 0.f;
#pragma unroll
    for (int i = 0; i < 16; ++i) {
        const int g = tid + i * THREADS;
        const float lw = lin_w[g];
        const float2 bv = buf[g];
        a0 = fmaf(bv.x, lw, a0);
        a1 = fmaf(bv.y, lw, a1);
    }
#pragma unroll
    for (int off = 32; off > 0; off >>= 1) {
        a0 += __shfl_down(a0, off);
        a1 += __shfl_down(a1, off);
    }
    const int lane = tid & 63, wid = tid >> 6;
    if (lane == 0) { red0[wid] = a0; red1[wid] = a1; }
    __syncthreads();
    if (tid == 0) {
        float s0 = 0.f, s1 = 0.f;
#pragma unroll
        for (int k = 0; k < THREADS / 64; ++k) { s0 += red0[k]; s1 += red1[k]; }
        const float lb = lin_b[0];
        out[row0]     = s0 + lb;
        out[row0 + 1] = s1 + lb;
    }
}

extern "C" void kernel_launch(void* const* d_in, const int* in_sizes, int n_in,
                              void* d_out, int out_size, void* d_ws, size_t ws_size,
                              hipStream_t stream) {
    // layout: [x, idx0, w0, idx1, w1, ..., idx5, w5, lin_w, lin_b]
    const float* x = (const float*)d_in[0];
    Ptrs P;
    for (int l = 0; l < NLAYER; ++l) {
        P.idx[l] = (const int*)d_in[1 + 2 * l];
        P.w[l]   = (const float*)d_in[2 + 2 * l];
    }
    const float* lin_w = (const float*)d_in[13];
    const float* lin_b = (const float*)d_in[14];
    float* out = (float*)d_out;

    const size_t hcf_bytes  = (size_t)NLAYER * G_DIM * sizeof(uint2);
    const size_t sidx_bytes = (size_t)NLAYER * G_DIM * sizeof(unsigned);
    if (ws_size >= hcf_bytes + sidx_bytes) {
        uint2*    hcf  = (uint2*)d_ws;
        unsigned* sidx = (unsigned*)((char*)d_ws + hcf_bytes);
        dim3 cgrid(G_DIM / 256, NLAYER);
        pack_kernel<<<cgrid, 256, 0, stream>>>(P, hcf, sidx);
        fused_ws_kernel<<<N_BATCH / ROWS, THREADS, 0, stream>>>(
            x, hcf, sidx, lin_w, lin_b, out);
    } else {
        fused_fallback_kernel<<<N_BATCH / 2, THREADS, 0, stream>>>(
            x, P, lin_w, lin_b, out);
    }
}